// Round 1
// baseline (1869.515 us; speedup 1.0000x reference)
//
#include <hip/hip_runtime.h>
#include <cstddef>

// learned_qp_solver: B=4096, NUM=256, NC=1530, IND=260, H=1024, OUT=1786, 5 iters.
//
// Key structural facts exploited:
//   A_control = [I; -I; Pd; -Pd; Pdd; -Pdd]  (Pd/Pdd = diff stencils / T, /T^2)
//   cost      = 3I + 2 Pd^T Pd + 2 Pdd^T Pdd   -> pentadiagonal SPD
//   cost_mat  = [[cost, e0],[e0^T, 0]]          -> banded Cholesky + border corr.
//   s_new = max(0, b_control - A_control x)     -> state per row is just (lamda, x)
//
// ws layout (bytes), total ~56 MB:
//   [0,            29261824)  NOt   fp32 [1786][B]   (neural_out transposed)
//   [29261824,     46039040)  h     fp32 [B][1024]   (dead after GEMM2; reused:)
//        lam fp32 [256][B] @ +0, Xa @ +4MB, Xb @ +8MB
//   [46039040,     54427648)  Wb    fp64 [256][B]    (solve temp)
//   [54427648,     58621952)  sst   fp32 [256][B]    (steer_samples transposed)
//   [58621952,     58630272)  fac   fp64 [1040]      (inv_d, l1, l2, z)

#define NUMV 256
#define QP_ITERS 5

// ---------------- fp32 tiled GEMM (64x64x16, 256 thr, 4x4/thread) ----------------
template<bool RELU, bool TRANS_OUT>
__global__ __launch_bounds__(256) void mlp_gemm(
    const float* __restrict__ A, const float* __restrict__ Bw,
    const float* __restrict__ bias, float* __restrict__ C,
    int M, int N, int K)
{
  __shared__ float As[16][68];
  __shared__ float Bs[16][68];
  const int tid = threadIdx.x;
  const int ty = tid >> 4, tx = tid & 15;
  const int m0 = blockIdx.x * 64, n0 = blockIdx.y * 64;
  const int lm = tid >> 2, lk = (tid & 3) * 4;
  const int lbk = tid >> 4, lbn = (tid & 15) * 4;
  float acc[4][4] = {};
  for (int k0 = 0; k0 < K; k0 += 16) {
    if (k0 + 16 <= K) {
      float4 av = *reinterpret_cast<const float4*>(&A[(size_t)(m0 + lm) * K + k0 + lk]);
      As[lk + 0][lm] = av.x; As[lk + 1][lm] = av.y;
      As[lk + 2][lm] = av.z; As[lk + 3][lm] = av.w;
    } else {
      for (int i = 0; i < 4; i++) {
        int kk = k0 + lk + i;
        As[lk + i][lm] = (kk < K) ? A[(size_t)(m0 + lm) * K + kk] : 0.f;
      }
    }
    const bool kok = (k0 + lbk) < K;
    if (kok && (n0 + 64) <= N) {
      *reinterpret_cast<float4*>(&Bs[lbk][lbn]) =
          *reinterpret_cast<const float4*>(&Bw[(size_t)(k0 + lbk) * N + n0 + lbn]);
    } else {
      for (int i = 0; i < 4; i++) {
        int nn = n0 + lbn + i;
        Bs[lbk][lbn + i] = (kok && nn < N) ? Bw[(size_t)(k0 + lbk) * N + nn] : 0.f;
      }
    }
    __syncthreads();
#pragma unroll
    for (int kk = 0; kk < 16; kk++) {
      float4 a4 = *reinterpret_cast<const float4*>(&As[kk][ty * 4]);
      float4 b4 = *reinterpret_cast<const float4*>(&Bs[kk][tx * 4]);
      const float av[4] = {a4.x, a4.y, a4.z, a4.w};
      const float bv[4] = {b4.x, b4.y, b4.z, b4.w};
#pragma unroll
      for (int i = 0; i < 4; i++)
#pragma unroll
        for (int j = 0; j < 4; j++) acc[i][j] = fmaf(av[i], bv[j], acc[i][j]);
    }
    __syncthreads();
  }
  if (!TRANS_OUT) {
#pragma unroll
    for (int i = 0; i < 4; i++) {
      const int m = m0 + ty * 4 + i;
#pragma unroll
      for (int j = 0; j < 4; j++) {
        const int n = n0 + tx * 4 + j;
        if (n < N) {
          float v = acc[i][j] + bias[n];
          if (RELU) v = fmaxf(v, 0.f);
          C[(size_t)m * N + n] = v;
        }
      }
    }
  } else {
#pragma unroll
    for (int j = 0; j < 4; j++) {
      const int n = n0 + tx * 4 + j;
      if (n < N) {
        const float bv = bias[n];
#pragma unroll
        for (int i = 0; i < 4; i++) {
          const int m = m0 + ty * 4 + i;
          float v = acc[i][j] + bv;
          if (RELU) v = fmaxf(v, 0.f);
          C[(size_t)n * M + m] = v;
        }
      }
    }
  }
}

// ---------------- transpose steer_samples [B][256] -> [256][B] ----------------
__global__ __launch_bounds__(256) void transpose_ss(
    const float* __restrict__ in, float* __restrict__ out, int R, int Cc)
{
  __shared__ float t[32][33];
  const int bx = blockIdx.x * 32, by = blockIdx.y * 32;
  const int x = threadIdx.x, y = threadIdx.y;
  for (int yy = y; yy < 32; yy += 8)
    t[yy][x] = in[(size_t)(by + yy) * Cc + bx + x];
  __syncthreads();
  for (int yy = y; yy < 32; yy += 8)
    out[(size_t)(bx + yy) * R + by + x] = t[x][yy];
}

// ---------------- fp64 banded Cholesky of cost (pentadiagonal) + z ----------------
__global__ void setup_factor(double* __restrict__ f)
{
  if (threadIdx.x != 0 || blockIdx.x != 0) return;
  const double T = 0.05, a = 1.0 / (T * T), b2 = a * a;
  double c0[256], c1[255], c2[254], dd[256], l1[256], l2[256];
  for (int j = 0; j < 256; j++) {
    double cd1 = (j == 0 || j == 255) ? 1.0 : 2.0;
    double cd2 = (j == 0 || j == 255) ? 1.0 : ((j == 1 || j == 254) ? 5.0 : 6.0);
    c0[j] = 3.0 + 2.0 * a * cd1 + 2.0 * b2 * cd2;
  }
  for (int j = 0; j < 255; j++)
    c1[j] = -2.0 * a + 2.0 * b2 * ((j == 0 || j == 254) ? -2.0 : -4.0);
  for (int j = 0; j < 254; j++) c2[j] = 2.0 * b2;
  dd[0] = sqrt(c0[0]); l1[0] = 0.0; l2[0] = 0.0;
  l1[1] = c1[0] / dd[0]; l2[1] = 0.0;
  dd[1] = sqrt(c0[1] - l1[1] * l1[1]);
  for (int j = 2; j < 256; j++) {
    l2[j] = c2[j - 2] / dd[j - 2];
    l1[j] = (c1[j - 1] - l2[j] * l1[j - 1]) / dd[j - 1];
    dd[j] = sqrt(c0[j] - l1[j] * l1[j] - l2[j] * l2[j]);
  }
  for (int j = 0; j < 256; j++) f[j] = 1.0 / dd[j];      // inv_d [0,256)
  for (int j = 0; j < 256; j++) f[256 + j] = l1[j];       // l1    [256,513) (pad)
  f[256 + 256] = 0.0;
  for (int j = 0; j < 256; j++) f[520 + j] = l2[j];       // l2    [520,778) (pad)
  f[520 + 256] = 0.0; f[520 + 257] = 0.0;
  // z = cost^{-1} e0
  double w[256], zz[256];
  w[0] = 1.0 / dd[0];
  w[1] = (-l1[1] * w[0]) / dd[1];
  for (int j = 2; j < 256; j++) w[j] = (-l1[j] * w[j - 1] - l2[j] * w[j - 2]) / dd[j];
  zz[255] = w[255] / dd[255];
  zz[254] = (w[254] - l1[255] * zz[255]) / dd[254];
  for (int j = 253; j >= 0; j--)
    zz[j] = (w[j] - l1[j + 1] * zz[j + 1] - l2[j + 2] * zz[j + 2]) / dd[j];
  for (int j = 0; j < 256; j++) f[784 + j] = zz[j];       // z [784,1040)
}

// ---------------- fused 5-iteration QP kernel, thread-per-row ----------------
__global__ __launch_bounds__(64) void qp_iter(
    const float* __restrict__ NOt,    // [1786][B]
    const float* __restrict__ sst,    // [256][B]
    const float* __restrict__ sinit,  // [B]
    const float* __restrict__ p_smax, const float* __restrict__ p_smin,
    const float* __restrict__ p_sdmax, const float* __restrict__ p_sdmin,
    const float* __restrict__ p_sddmax, const float* __restrict__ p_sddmin,
    const double* __restrict__ fac,
    float* __restrict__ lam,          // [256][B]
    float* __restrict__ Xa, float* __restrict__ Xb,  // [256][B]
    double* __restrict__ Wb,          // [256][B]
    float* __restrict__ out, int B)
{
  __shared__ double s_invd[256], s_l1[257], s_l2[258], s_z[256];
  const int tid = threadIdx.x;
  for (int i = tid; i < 256; i += 64) { s_invd[i] = fac[i]; s_z[i] = fac[784 + i]; }
  for (int i = tid; i < 257; i += 64) s_l1[i] = fac[256 + i];
  for (int i = tid; i < 258; i += 64) s_l2[i] = fac[520 + i];
  __syncthreads();

  const int r = blockIdx.x * 64 + tid;
  const float smax = *p_smax, smin = *p_smin;
  const float sdmax = *p_sdmax, sdmin = *p_sdmin;
  const float sddmax = *p_sddmax, sddmin = *p_sddmin;
  const float invT = 20.f, invT2 = 400.f;
  const float K0 = smax + smin, K1 = sdmax + sdmin, K2 = sddmax + sddmin;
  const double b_eq = (double)sinit[r];

  const size_t primOff = (size_t)B * NUMV;
  const size_t fpOff = primOff + (size_t)QP_ITERS * B;
  const size_t accPOff = fpOff + (size_t)QP_ITERS * B;
  const size_t accFOff = accPOff + (size_t)B;

  float accP = 0.f, accF = 0.f;
  const float* XP = Xa;
  float* XN = Xb;

  for (int it = 0; it < QP_ITERS; ++it) {
    // ---- Phase A: rhs(j) = lam + ss + b_aug@A_control, fused fwd substitution
    double w1 = 0.0, w2 = 0.0;
    float D1p = 0.f, D2p = 0.f, D2pp = 0.f;
    float xp0 = 0.f, xp1 = 0.f, xp2 = 0.f;
    if (it > 0) {
      xp0 = XP[(size_t)0 * B + r]; xp1 = XP[(size_t)1 * B + r]; xp2 = XP[(size_t)2 * B + r];
    }
    for (int j = 0; j < 256; j++) {
      float D0, D1c = 0.f, D2c = 0.f;
      if (it == 0) {
        float sa = fmaxf(0.f, NOt[(size_t)(256 + j) * B + r]);
        float sb = fmaxf(0.f, NOt[(size_t)(512 + j) * B + r]);
        D0 = K0 - sa + sb;
        if (j < 255) {
          float sc = fmaxf(0.f, NOt[(size_t)(768 + j) * B + r]);
          float sd = fmaxf(0.f, NOt[(size_t)(1023 + j) * B + r]);
          D1c = K1 - sc + sd;
        }
        if (j < 254) {
          float se = fmaxf(0.f, NOt[(size_t)(1278 + j) * B + r]);
          float sf = fmaxf(0.f, NOt[(size_t)(1532 + j) * B + r]);
          D2c = K2 - se + sf;
        }
      } else {
        D0 = fminf(smax, xp0) + fmaxf(smin, xp0);
        if (j < 255) { float vp = (xp1 - xp0) * invT; D1c = fminf(sdmax, vp) + fmaxf(sdmin, vp); }
        if (j < 254) { float ap = (xp2 - 2.f * xp1 + xp0) * invT2; D2c = fminf(sddmax, ap) + fmaxf(sddmin, ap); }
        xp0 = xp1; xp1 = xp2;
        xp2 = (j + 3 < 256) ? XP[(size_t)(j + 3) * B + r] : 0.f;
      }
      float q = D0 + (D1p - D1c) * invT + (D2pp - 2.f * D2p + D2c) * invT2;
      D1p = D1c; D2pp = D2p; D2p = D2c;
      float lamj = (it == 0) ? NOt[(size_t)j * B + r] : lam[(size_t)j * B + r];
      double rhs = (double)lamj + (double)sst[(size_t)j * B + r] + (double)q;
      double wj = (rhs - s_l1[j] * w1 - s_l2[j] * w2) * s_invd[j];
      Wb[(size_t)j * B + r] = wj;
      w2 = w1; w1 = wj;
    }
    // ---- Phase B: backward substitution (in place), border correction mu
    double y1 = 0.0, y2 = 0.0;
    for (int j = 255; j >= 0; j--) {
      double yj = (Wb[(size_t)j * B + r] - s_l1[j + 1] * y1 - s_l2[j + 2] * y2) * s_invd[j];
      Wb[(size_t)j * B + r] = yj;
      y2 = y1; y1 = yj;
    }
    const double mu = (y1 - b_eq) / s_z[0];
    // ---- Phase C: x = y - mu z; residual, s_new, lamda update, norms
    float E1p = 0.f, E2p = 0.f, E2pp = 0.f;
    float x0 = (float)(Wb[(size_t)0 * B + r] - mu * s_z[0]);
    float x1v = (float)(Wb[(size_t)1 * B + r] - mu * s_z[1]);
    float x2v = (float)(Wb[(size_t)2 * B + r] - mu * s_z[2]);
    if (it > 0) {
      xp0 = XP[(size_t)0 * B + r]; xp1 = XP[(size_t)1 * B + r]; xp2 = XP[(size_t)2 * B + r];
    }
    double res2 = 0.0, fps2 = 0.0, fpl2 = 0.0;
    for (int j = 0; j < 256; j++) {
      const bool h1 = j < 255, h2 = j < 254;
      float v = 0.f, aa = 0.f;
      if (h1) v = (x1v - x0) * invT;
      if (h2) aa = (x2v - 2.f * x1v + x0) * invT2;
      float rv0a = fmaxf(0.f, x0 - smax), rv0b = fmaxf(0.f, smin - x0);
      float E0 = rv0a - rv0b;
      float E1c = 0.f, E2c = 0.f;
      float rv1a = 0.f, rv1b = 0.f, rv2a = 0.f, rv2b = 0.f;
      if (h1) { rv1a = fmaxf(0.f, v - sdmax); rv1b = fmaxf(0.f, sdmin - v); E1c = rv1a - rv1b; }
      if (h2) { rv2a = fmaxf(0.f, aa - sddmax); rv2b = fmaxf(0.f, sddmin - aa); E2c = rv2a - rv2b; }
      res2 += (double)(rv0a * rv0a + rv0b * rv0b + rv1a * rv1a + rv1b * rv1b + rv2a * rv2a + rv2b * rv2b);
      float sn0a = fmaxf(0.f, smax - x0), sn0b = fmaxf(0.f, x0 - smin);
      float sn1a = 0.f, sn1b = 0.f, sn2a = 0.f, sn2b = 0.f;
      if (h1) { sn1a = fmaxf(0.f, sdmax - v); sn1b = fmaxf(0.f, v - sdmin); }
      if (h2) { sn2a = fmaxf(0.f, sddmax - aa); sn2b = fmaxf(0.f, aa - sddmin); }
      float sp0a, sp0b, sp1a = 0.f, sp1b = 0.f, sp2a = 0.f, sp2b = 0.f;
      if (it == 0) {
        sp0a = fmaxf(0.f, NOt[(size_t)(256 + j) * B + r]);
        sp0b = fmaxf(0.f, NOt[(size_t)(512 + j) * B + r]);
        if (h1) {
          sp1a = fmaxf(0.f, NOt[(size_t)(768 + j) * B + r]);
          sp1b = fmaxf(0.f, NOt[(size_t)(1023 + j) * B + r]);
        }
        if (h2) {
          sp2a = fmaxf(0.f, NOt[(size_t)(1278 + j) * B + r]);
          sp2b = fmaxf(0.f, NOt[(size_t)(1532 + j) * B + r]);
        }
      } else {
        float vp = 0.f, ap = 0.f;
        if (h1) vp = (xp1 - xp0) * invT;
        if (h2) ap = (xp2 - 2.f * xp1 + xp0) * invT2;
        sp0a = fmaxf(0.f, smax - xp0); sp0b = fmaxf(0.f, xp0 - smin);
        if (h1) { sp1a = fmaxf(0.f, sdmax - vp); sp1b = fmaxf(0.f, vp - sdmin); }
        if (h2) { sp2a = fmaxf(0.f, sddmax - ap); sp2b = fmaxf(0.f, ap - sddmin); }
        xp0 = xp1; xp1 = xp2;
        xp2 = (j + 3 < 256) ? XP[(size_t)(j + 3) * B + r] : 0.f;
      }
      float d0a = sp0a - sn0a, d0b = sp0b - sn0b;
      float d1a = sp1a - sn1a, d1b = sp1b - sn1b;
      float d2a = sp2a - sn2a, d2b = sp2b - sn2b;
      fps2 += (double)(d0a * d0a + d0b * d0b + d1a * d1a + d1b * d1b + d2a * d2a + d2b * d2b);
      float lamj = (it == 0) ? NOt[(size_t)j * B + r] : lam[(size_t)j * B + r];
      float lnew = lamj - (E0 + (E1p - E1c) * invT + (E2pp - 2.f * E2p + E2c) * invT2);
      float dl = lamj - lnew;
      fpl2 += (double)(dl * dl);
      lam[(size_t)j * B + r] = lnew;
      XN[(size_t)j * B + r] = x0;
      if (it == QP_ITERS - 1) out[(size_t)r * NUMV + j] = x0;
      E1p = E1c; E2pp = E2p; E2p = E2c;
      x0 = x1v; x1v = x2v;
      x2v = (j + 3 < 256) ? (float)(Wb[(size_t)(j + 3) * B + r] - mu * s_z[j + 3]) : 0.f;
    }
    float res = sqrtf((float)res2);
    float fp = sqrtf((float)fps2) + sqrtf((float)fpl2);
    out[primOff + (size_t)it * B + r] = res;
    out[fpOff + (size_t)it * B + r] = fp;
    accP += res; accF += fp;
    const float* tmp = XP; XP = XN; XN = (float*)tmp;
  }
  out[accPOff + r] = accP * (1.f / QP_ITERS);
  out[accFOff + r] = accF * (1.f / QP_ITERS);
}

extern "C" void kernel_launch(void* const* d_in, const int* in_sizes, int n_in,
                              void* d_out, int out_size, void* d_ws, size_t ws_size,
                              hipStream_t stream)
{
  const float* inp = (const float*)d_in[0];       // [B][260]
  const float* sinit = (const float*)d_in[1];     // [B][1]
  const float* ssamp = (const float*)d_in[2];     // [B][256]
  const float* p_smax = (const float*)d_in[3];
  const float* p_smin = (const float*)d_in[4];
  const float* p_sdmax = (const float*)d_in[5];
  const float* p_sdmin = (const float*)d_in[6];
  const float* p_sddmax = (const float*)d_in[7];
  const float* p_sddmin = (const float*)d_in[8];
  // d_in[9]=median_, d_in[10]=iqr_ : unused by reference (inp_norm = inp)
  const float* W1 = (const float*)d_in[11];       // [260][1024]
  const float* b1 = (const float*)d_in[12];       // [1024]
  const float* W2 = (const float*)d_in[13];       // [1024][1786]
  const float* b2 = (const float*)d_in[14];       // [1786]
  float* out = (float*)d_out;

  const int B = in_sizes[1];                      // 4096
  const int IND = in_sizes[9];                    // 260
  const int H = in_sizes[12];                     // 1024
  const int OUTN = in_sizes[14];                  // 1786

  char* ws = (char*)d_ws;
  float* NOt = (float*)ws;                                    // [1786][B]
  char* hreg = ws + (size_t)OUTN * B * 4;                     // 29,261,824
  float* h = (float*)hreg;                                    // [B][H]
  float* lam = (float*)hreg;                                  // reuse of h
  float* Xa = (float*)(hreg + (size_t)NUMV * B * 4);
  float* Xb = (float*)(hreg + (size_t)2 * NUMV * B * 4);
  char* after_h = hreg + (size_t)B * H * 4;                   // 46,039,040
  double* Wb = (double*)after_h;                              // [256][B] fp64
  char* after_w = after_h + (size_t)NUMV * B * 8;             // 54,427,648
  float* sst = (float*)after_w;                               // [256][B]
  double* fac = (double*)(after_w + (size_t)NUMV * B * 4);    // 1040 doubles

  setup_factor<<<1, 64, 0, stream>>>(fac);
  {
    dim3 g(NUMV / 32, B / 32), blk(32, 8);
    transpose_ss<<<g, blk, 0, stream>>>(ssamp, sst, B, NUMV);
  }
  {
    dim3 g(B / 64, H / 64);
    mlp_gemm<true, false><<<g, 256, 0, stream>>>(inp, W1, b1, h, B, H, IND);
  }
  {
    dim3 g(B / 64, (OUTN + 63) / 64);
    mlp_gemm<false, true><<<g, 256, 0, stream>>>(h, W2, b2, NOt, B, OUTN, H);
  }
  qp_iter<<<B / 64, 64, 0, stream>>>(NOt, sst, sinit,
                                     p_smax, p_smin, p_sdmax, p_sdmin, p_sddmax, p_sddmin,
                                     fac, lam, Xa, Xb, Wb, out, B);
}

// Round 4
// 656.361 us; speedup vs baseline: 2.8483x; 2.8483x over previous
//
#include <hip/hip_runtime.h>
#include <cstddef>

// learned_qp_solver: B=4096, NUM=256, NC=1530, IND=260, H=1024, OUT=1786, 5 iters.
//
// Structure exploited:
//   A_control = [I; -I; Pd; -Pd; Pdd; -Pdd]       (diff stencils / T, /T^2)
//   cost      = 3I + 2 Pd^T Pd + 2 Pdd^T Pdd      -> pentadiagonal SPD
//   KKT solve closed form:  x = G v + (b_eq/z0) z,  G = C^{-1} - z z^T / z0
//   -> per-iteration solve is a 4096x256x256 GEMM (fully parallel),
//      everything else is row-local stencils (one block per row).
//
// ws layout (bytes), ~46.8 MB total:
//   [0,          29261824)  NO    fp32 [B][1786]   neural_out
//   [29261824,   46039040)  h     fp32 [B][1024]   dead after GEMM2, reused as:
//        V  @ +0, Xa @ +4MB, Xb @ +8MB, lam @ +12MB   (each fp32 [B][256])
//   [46039040,   46301184)  G     fp32 [256][256]
//   [46301184,   46302208)  zc    fp32 [256]       z/z0
//   [46302208,   46310592)  fac   fp64 [1048]      inv_d, l1, l2, z
//   [46310592,   46834880)  Wtmp  fp64 [256][256]  G-build scratch

#define NUMV 256
#define QP_ITERS 5

// ---------------- fp32 tiled GEMM (64x64x16, 256 thr, 4x4/thread) ----------------
template<bool RELU>
__global__ __launch_bounds__(256) void mlp_gemm(
    const float* __restrict__ A, const float* __restrict__ Bw,
    const float* __restrict__ bias, float* __restrict__ C,
    int M, int N, int K)
{
  __shared__ float As[16][68];
  __shared__ float Bs[16][68];
  const int tid = threadIdx.x;
  const int ty = tid >> 4, tx = tid & 15;
  const int m0 = blockIdx.x * 64, n0 = blockIdx.y * 64;
  const int lm = tid >> 2, lk = (tid & 3) * 4;
  const int lbk = tid >> 4, lbn = (tid & 15) * 4;
  float acc[4][4] = {};
  for (int k0 = 0; k0 < K; k0 += 16) {
    if (k0 + 16 <= K) {
      float4 av = *reinterpret_cast<const float4*>(&A[(size_t)(m0 + lm) * K + k0 + lk]);
      As[lk + 0][lm] = av.x; As[lk + 1][lm] = av.y;
      As[lk + 2][lm] = av.z; As[lk + 3][lm] = av.w;
    } else {
      for (int i = 0; i < 4; i++) {
        int kk = k0 + lk + i;
        As[lk + i][lm] = (kk < K) ? A[(size_t)(m0 + lm) * K + kk] : 0.f;
      }
    }
    const bool kok = (k0 + lbk) < K;
    if (kok && (n0 + 64) <= N) {
      *reinterpret_cast<float4*>(&Bs[lbk][lbn]) =
          *reinterpret_cast<const float4*>(&Bw[(size_t)(k0 + lbk) * N + n0 + lbn]);
    } else {
      for (int i = 0; i < 4; i++) {
        int nn = n0 + lbn + i;
        Bs[lbk][lbn + i] = (kok && nn < N) ? Bw[(size_t)(k0 + lbk) * N + nn] : 0.f;
      }
    }
    __syncthreads();
#pragma unroll
    for (int kk = 0; kk < 16; kk++) {
      float4 a4 = *reinterpret_cast<const float4*>(&As[kk][ty * 4]);
      float4 b4 = *reinterpret_cast<const float4*>(&Bs[kk][tx * 4]);
      const float av[4] = {a4.x, a4.y, a4.z, a4.w};
      const float bv[4] = {b4.x, b4.y, b4.z, b4.w};
#pragma unroll
      for (int i = 0; i < 4; i++)
#pragma unroll
        for (int j = 0; j < 4; j++) acc[i][j] = fmaf(av[i], bv[j], acc[i][j]);
    }
    __syncthreads();
  }
#pragma unroll
  for (int i = 0; i < 4; i++) {
    const int m = m0 + ty * 4 + i;
#pragma unroll
    for (int j = 0; j < 4; j++) {
      const int n = n0 + tx * 4 + j;
      if (n < N) {
        float v = acc[i][j] + bias[n];
        if (RELU) v = fmaxf(v, 0.f);
        C[(size_t)m * N + n] = v;
      }
    }
  }
}

// ---- solve GEMM: X[m][n] = sum_k V[m][k] G[k][n] + beq[m]*zc[n]  (all dims tile-exact)
__global__ __launch_bounds__(256) void gemm_solve(
    const float* __restrict__ V, const float* __restrict__ G,
    const float* __restrict__ beq, const float* __restrict__ zc,
    float* __restrict__ X, int M, int N, int K)
{
  __shared__ float As[16][68];
  __shared__ float Bs[16][68];
  const int tid = threadIdx.x;
  const int ty = tid >> 4, tx = tid & 15;
  const int m0 = blockIdx.x * 64, n0 = blockIdx.y * 64;
  const int lm = tid >> 2, lk = (tid & 3) * 4;
  const int lbk = tid >> 4, lbn = (tid & 15) * 4;
  float acc[4][4] = {};
  for (int k0 = 0; k0 < K; k0 += 16) {
    float4 av = *reinterpret_cast<const float4*>(&V[(size_t)(m0 + lm) * K + k0 + lk]);
    As[lk + 0][lm] = av.x; As[lk + 1][lm] = av.y;
    As[lk + 2][lm] = av.z; As[lk + 3][lm] = av.w;
    *reinterpret_cast<float4*>(&Bs[lbk][lbn]) =
        *reinterpret_cast<const float4*>(&G[(size_t)(k0 + lbk) * N + n0 + lbn]);
    __syncthreads();
#pragma unroll
    for (int kk = 0; kk < 16; kk++) {
      float4 a4 = *reinterpret_cast<const float4*>(&As[kk][ty * 4]);
      float4 b4 = *reinterpret_cast<const float4*>(&Bs[kk][tx * 4]);
      const float av2[4] = {a4.x, a4.y, a4.z, a4.w};
      const float bv2[4] = {b4.x, b4.y, b4.z, b4.w};
#pragma unroll
      for (int i = 0; i < 4; i++)
#pragma unroll
        for (int j = 0; j < 4; j++) acc[i][j] = fmaf(av2[i], bv2[j], acc[i][j]);
    }
    __syncthreads();
  }
#pragma unroll
  for (int i = 0; i < 4; i++) {
    const int m = m0 + ty * 4 + i;
    const float be = beq[m];
#pragma unroll
    for (int j = 0; j < 4; j++) {
      const int n = n0 + tx * 4 + j;
      X[(size_t)m * N + n] = acc[i][j] + be * zc[n];
    }
  }
}

// ---------------- fp64 banded Cholesky of cost (pentadiagonal) + z ----------------
__global__ void setup_factor(double* __restrict__ f)
{
  if (threadIdx.x != 0 || blockIdx.x != 0) return;
  const double T = 0.05, a = 1.0 / (T * T), b2 = a * a;
  double c0[256], c1[255], c2[254], dd[256], l1[256], l2[256];
  for (int j = 0; j < 256; j++) {
    double cd1 = (j == 0 || j == 255) ? 1.0 : 2.0;
    double cd2 = (j == 0 || j == 255) ? 1.0 : ((j == 1 || j == 254) ? 5.0 : 6.0);
    c0[j] = 3.0 + 2.0 * a * cd1 + 2.0 * b2 * cd2;
  }
  for (int j = 0; j < 255; j++)
    c1[j] = -2.0 * a + 2.0 * b2 * ((j == 0 || j == 254) ? -2.0 : -4.0);
  for (int j = 0; j < 254; j++) c2[j] = 2.0 * b2;
  dd[0] = sqrt(c0[0]); l1[0] = 0.0; l2[0] = 0.0;
  l1[1] = c1[0] / dd[0]; l2[1] = 0.0;
  dd[1] = sqrt(c0[1] - l1[1] * l1[1]);
  for (int j = 2; j < 256; j++) {
    l2[j] = c2[j - 2] / dd[j - 2];
    l1[j] = (c1[j - 1] - l2[j] * l1[j - 1]) / dd[j - 1];
    dd[j] = sqrt(c0[j] - l1[j] * l1[j] - l2[j] * l2[j]);
  }
  for (int j = 0; j < 256; j++) f[j] = 1.0 / dd[j];       // inv_d [0,256)
  for (int j = 0; j < 256; j++) f[256 + j] = l1[j];        // l1    [256,513)
  f[256 + 256] = 0.0;
  for (int j = 0; j < 256; j++) f[520 + j] = l2[j];        // l2    [520,778)
  f[520 + 256] = 0.0; f[520 + 257] = 0.0;
  // z = cost^{-1} e0
  double w[256], zz[256];
  w[0] = 1.0 / dd[0];
  w[1] = (-l1[1] * w[0]) / dd[1];
  for (int j = 2; j < 256; j++) w[j] = (-l1[j] * w[j - 1] - l2[j] * w[j - 2]) / dd[j];
  zz[255] = w[255] / dd[255];
  zz[254] = (w[254] - l1[255] * zz[255]) / dd[254];
  for (int j = 253; j >= 0; j--)
    zz[j] = (w[j] - l1[j + 1] * zz[j + 1] - l2[j + 2] * zz[j + 2]) / dd[j];
  for (int j = 0; j < 256; j++) f[784 + j] = zz[j];        // z [784,1040)
}

// ---------------- build G = C^{-1} - z z^T/z0 (fp32), one column per thread ------
__global__ __launch_bounds__(256) void build_g(
    const double* __restrict__ fac, double* __restrict__ Wtmp,
    float* __restrict__ G, float* __restrict__ zc)
{
  __shared__ double invd[256], l1[257], l2[258], z[256];
  const int t = threadIdx.x;
  invd[t] = fac[t]; z[t] = fac[784 + t];
  l1[t] = fac[256 + t];
  if (t == 0) l1[256] = fac[256 + 256];
  l2[t] = fac[520 + t];
  if (t < 2) l2[256 + t] = fac[520 + 256 + t];
  __syncthreads();
  double w1 = 0.0, w2 = 0.0;
#pragma unroll 4
  for (int j = 0; j < 256; j++) {
    double rhs = (j == t) ? 1.0 : 0.0;
    double wj = (rhs - l1[j] * w1 - l2[j] * w2) * invd[j];
    Wtmp[(size_t)j * 256 + t] = wj;
    w2 = w1; w1 = wj;
  }
  const double zr = z[t] / z[0];
  double y1 = 0.0, y2 = 0.0;
#pragma unroll 4
  for (int j = 255; j >= 0; j--) {
    double yj = (Wtmp[(size_t)j * 256 + t] - l1[j + 1] * y1 - l2[j + 2] * y2) * invd[j];
    G[(size_t)j * 256 + t] = (float)(yj - z[j] * zr);
    y2 = y1; y1 = yj;
  }
  zc[t] = (float)zr;
}

// ---------------- initial rhs V0 = lam0 + ss + b_aug0 @ A_control ----------------
__global__ __launch_bounds__(256) void init_v(
    const float* __restrict__ NO, const float* __restrict__ ss,
    const float* __restrict__ p_smax, const float* __restrict__ p_smin,
    const float* __restrict__ p_sdmax, const float* __restrict__ p_sdmin,
    const float* __restrict__ p_sddmax, const float* __restrict__ p_sddmin,
    float* __restrict__ V, int B)
{
  __shared__ float d1s[258], d2s[258];
  const int r = blockIdx.x, j = threadIdx.x;
  const float K0 = *p_smax + *p_smin, K1 = *p_sdmax + *p_sdmin, K2 = *p_sddmax + *p_sddmin;
  const float invT = 20.f, invT2 = 400.f;
  const float* no = NO + (size_t)r * 1786;
  float s1 = fmaxf(0.f, no[256 + j]), s2 = fmaxf(0.f, no[512 + j]);
  float D0 = K0 - s1 + s2;
  float D1 = 0.f, D2 = 0.f;
  if (j < 255) D1 = K1 - fmaxf(0.f, no[768 + j]) + fmaxf(0.f, no[1023 + j]);
  if (j < 254) D2 = K2 - fmaxf(0.f, no[1278 + j]) + fmaxf(0.f, no[1532 + j]);
  d1s[2 + j] = D1; d2s[2 + j] = D2;
  if (j < 2) { d1s[j] = 0.f; d2s[j] = 0.f; }
  __syncthreads();
  float qn = D0 + (d1s[j + 1] - d1s[j + 2]) * invT
                + (d2s[j] - 2.f * d2s[j + 1] + d2s[j + 2]) * invT2;
  V[(size_t)r * NUMV + j] = no[j] + ss[(size_t)r * NUMV + j] + qn;
}

// ---------------- per-iteration update: one block per row ----------------
__global__ __launch_bounds__(256) void qp_update(
    const float* __restrict__ X, const float* __restrict__ Xp,
    const float* __restrict__ NO, float* lam,
    const float* __restrict__ ss,
    const float* __restrict__ p_smax, const float* __restrict__ p_smin,
    const float* __restrict__ p_sdmax, const float* __restrict__ p_sdmin,
    const float* __restrict__ p_sddmax, const float* __restrict__ p_sddmin,
    float* __restrict__ Vn, float* __restrict__ out, int B, int it)
{
  __shared__ float xs[258], xps[258];
  __shared__ float e1s[258], e2s[258], d1s[258], d2s[258];
  __shared__ double red[3][4];
  const int r = blockIdx.x, j = threadIdx.x;
  const float smax = *p_smax, smin = *p_smin;
  const float sdmax = *p_sdmax, sdmin = *p_sdmin;
  const float sddmax = *p_sddmax, sddmin = *p_sddmin;
  const float invT = 20.f, invT2 = 400.f;

  const float x0 = X[(size_t)r * NUMV + j];
  xs[j] = x0;
  if (j < 2) xs[256 + j] = 0.f;
  float xp0 = 0.f;
  if (it > 0) {
    xp0 = Xp[(size_t)r * NUMV + j];
    xps[j] = xp0;
    if (j < 2) xps[256 + j] = 0.f;
  }
  __syncthreads();

  const bool h1 = j < 255, h2 = j < 254;
  const float x1 = xs[j + 1], x2 = xs[j + 2];
  const float v = (x1 - x0) * invT;
  const float aa = (x2 - 2.f * x1 + x0) * invT2;

  // residual components rv = max(0, As - b_control)
  float rv0a = fmaxf(0.f, x0 - smax), rv0b = fmaxf(0.f, smin - x0);
  float rv1a = 0.f, rv1b = 0.f, rv2a = 0.f, rv2b = 0.f;
  float E1 = 0.f, E2 = 0.f;
  const float E0 = rv0a - rv0b;
  if (h1) { rv1a = fmaxf(0.f, v - sdmax); rv1b = fmaxf(0.f, sdmin - v); E1 = rv1a - rv1b; }
  if (h2) { rv2a = fmaxf(0.f, aa - sddmax); rv2b = fmaxf(0.f, sddmin - aa); E2 = rv2a - rv2b; }
  double res2 = (double)(rv0a * rv0a + rv0b * rv0b + rv1a * rv1a + rv1b * rv1b
                       + rv2a * rv2a + rv2b * rv2b);

  // s_new components
  const float sn0a = fmaxf(0.f, smax - x0), sn0b = fmaxf(0.f, x0 - smin);
  float sn1a = 0.f, sn1b = 0.f, sn2a = 0.f, sn2b = 0.f;
  if (h1) { sn1a = fmaxf(0.f, sdmax - v); sn1b = fmaxf(0.f, v - sdmin); }
  if (h2) { sn2a = fmaxf(0.f, sddmax - aa); sn2b = fmaxf(0.f, aa - sddmin); }

  // D for next rhs (b_aug_next @ A_control stencil inputs)
  const float D0n = fminf(smax, x0) + fmaxf(smin, x0);
  const float D1n = h1 ? (fminf(sdmax, v) + fmaxf(sdmin, v)) : 0.f;
  const float D2n = h2 ? (fminf(sddmax, aa) + fmaxf(sddmin, aa)) : 0.f;

  // s_prev components
  float sp0a, sp0b, sp1a = 0.f, sp1b = 0.f, sp2a = 0.f, sp2b = 0.f;
  if (it == 0) {
    const float* no = NO + (size_t)r * 1786;
    sp0a = fmaxf(0.f, no[256 + j]); sp0b = fmaxf(0.f, no[512 + j]);
    if (h1) { sp1a = fmaxf(0.f, no[768 + j]); sp1b = fmaxf(0.f, no[1023 + j]); }
    if (h2) { sp2a = fmaxf(0.f, no[1278 + j]); sp2b = fmaxf(0.f, no[1532 + j]); }
  } else {
    const float xp1 = xps[j + 1], xp2 = xps[j + 2];
    const float vp = (xp1 - xp0) * invT;
    const float ap = (xp2 - 2.f * xp1 + xp0) * invT2;
    sp0a = fmaxf(0.f, smax - xp0); sp0b = fmaxf(0.f, xp0 - smin);
    if (h1) { sp1a = fmaxf(0.f, sdmax - vp); sp1b = fmaxf(0.f, vp - sdmin); }
    if (h2) { sp2a = fmaxf(0.f, sddmax - ap); sp2b = fmaxf(0.f, ap - sddmin); }
  }
  const float d0a = sp0a - sn0a, d0b = sp0b - sn0b;
  const float d1a = sp1a - sn1a, d1b = sp1b - sn1b;
  const float d2a = sp2a - sn2a, d2b = sp2b - sn2b;
  double fps2 = (double)(d0a * d0a + d0b * d0b + d1a * d1a + d1b * d1b
                       + d2a * d2a + d2b * d2b);

  e1s[2 + j] = E1; e2s[2 + j] = E2; d1s[2 + j] = D1n; d2s[2 + j] = D2n;
  if (j < 2) { e1s[j] = 0.f; e2s[j] = 0.f; d1s[j] = 0.f; d2s[j] = 0.f; }
  __syncthreads();

  const float lamj = (it == 0) ? NO[(size_t)r * 1786 + j] : lam[(size_t)r * NUMV + j];
  const float lnew = lamj - (E0 + (e1s[j + 1] - e1s[j + 2]) * invT
                                + (e2s[j] - 2.f * e2s[j + 1] + e2s[j + 2]) * invT2);
  const float dl = lamj - lnew;
  double fpl2 = (double)(dl * dl);
  lam[(size_t)r * NUMV + j] = lnew;

  const size_t primOff = (size_t)B * NUMV;
  const size_t fpOff = primOff + (size_t)QP_ITERS * B;
  if (it < QP_ITERS - 1) {
    float qn = D0n + (d1s[j + 1] - d1s[j + 2]) * invT
                   + (d2s[j] - 2.f * d2s[j + 1] + d2s[j + 2]) * invT2;
    Vn[(size_t)r * NUMV + j] = lnew + ss[(size_t)r * NUMV + j] + qn;
  } else {
    out[(size_t)r * NUMV + j] = x0;
  }

  // block-reduce res2, fps2, fpl2
  for (int o = 32; o > 0; o >>= 1) {
    res2 += __shfl_down(res2, o);
    fps2 += __shfl_down(fps2, o);
    fpl2 += __shfl_down(fpl2, o);
  }
  const int wid = j >> 6, lane = j & 63;
  if (lane == 0) { red[0][wid] = res2; red[1][wid] = fps2; red[2][wid] = fpl2; }
  __syncthreads();
  if (j == 0) {
    double r2 = red[0][0] + red[0][1] + red[0][2] + red[0][3];
    double s2_ = red[1][0] + red[1][1] + red[1][2] + red[1][3];
    double l2_ = red[2][0] + red[2][1] + red[2][2] + red[2][3];
    out[primOff + (size_t)it * B + r] = sqrtf((float)r2);
    out[fpOff + (size_t)it * B + r] = sqrtf((float)s2_) + sqrtf((float)l2_);
  }
}

// ---------------- final acc_primal / acc_fixed ----------------
__global__ __launch_bounds__(256) void accum_out(float* __restrict__ out, int B)
{
  const int r = blockIdx.x * 256 + threadIdx.x;
  const size_t primOff = (size_t)B * NUMV;
  const size_t fpOff = primOff + (size_t)QP_ITERS * B;
  const size_t accPOff = fpOff + (size_t)QP_ITERS * B;
  const size_t accFOff = accPOff + (size_t)B;
  float sp = 0.f, sf = 0.f;
  for (int it = 0; it < QP_ITERS; it++) {
    sp += out[primOff + (size_t)it * B + r];
    sf += out[fpOff + (size_t)it * B + r];
  }
  out[accPOff + r] = sp * (1.f / QP_ITERS);
  out[accFOff + r] = sf * (1.f / QP_ITERS);
}

extern "C" void kernel_launch(void* const* d_in, const int* in_sizes, int n_in,
                              void* d_out, int out_size, void* d_ws, size_t ws_size,
                              hipStream_t stream)
{
  const float* inp = (const float*)d_in[0];       // [B][260]
  const float* sinit = (const float*)d_in[1];     // [B][1]
  const float* ssamp = (const float*)d_in[2];     // [B][256]
  const float* p_smax = (const float*)d_in[3];
  const float* p_smin = (const float*)d_in[4];
  const float* p_sdmax = (const float*)d_in[5];
  const float* p_sdmin = (const float*)d_in[6];
  const float* p_sddmax = (const float*)d_in[7];
  const float* p_sddmin = (const float*)d_in[8];
  const float* W1 = (const float*)d_in[11];       // [260][1024]
  const float* b1 = (const float*)d_in[12];       // [1024]
  const float* W2 = (const float*)d_in[13];       // [1024][1786]
  const float* b2 = (const float*)d_in[14];       // [1786]
  float* out = (float*)d_out;

  const int B = in_sizes[1];                      // 4096
  const int IND = in_sizes[9];                    // 260
  const int H = in_sizes[12];                     // 1024
  const int OUTN = in_sizes[14];                  // 1786

  char* ws = (char*)d_ws;
  float* NO = (float*)ws;                                     // [B][1786]
  char* hreg = ws + (size_t)B * OUTN * 4;                     // 29,261,824
  float* h = (float*)hreg;                                    // [B][1024]
  float* V = (float*)hreg;
  float* Xa = (float*)(hreg + (size_t)B * NUMV * 4);
  float* Xb = (float*)(hreg + (size_t)2 * B * NUMV * 4);
  float* lam = (float*)(hreg + (size_t)3 * B * NUMV * 4);
  char* after_h = hreg + (size_t)B * H * 4;                   // 46,039,040
  float* G = (float*)after_h;                                 // [256][256] fp32
  float* zc = (float*)(after_h + 262144);                     // [256]
  double* fac = (double*)(after_h + 262144 + 1024);           // 1048 doubles
  double* Wtmp = (double*)(after_h + 262144 + 1024 + 8384);   // [256][256] fp64

  setup_factor<<<1, 64, 0, stream>>>(fac);
  build_g<<<1, 256, 0, stream>>>(fac, Wtmp, G, zc);
  {
    dim3 g(B / 64, H / 64);
    mlp_gemm<true><<<g, 256, 0, stream>>>(inp, W1, b1, h, B, H, IND);
  }
  {
    dim3 g(B / 64, (OUTN + 63) / 64);
    mlp_gemm<false><<<g, 256, 0, stream>>>(h, W2, b2, NO, B, OUTN, H);
  }
  init_v<<<B, 256, 0, stream>>>(NO, ssamp, p_smax, p_smin, p_sdmax, p_sdmin,
                                p_sddmax, p_sddmin, V, B);
  float* Xcur = Xa;
  float* Xprev = Xb;
  for (int it = 0; it < QP_ITERS; it++) {
    dim3 g(B / 64, NUMV / 64);
    gemm_solve<<<g, 256, 0, stream>>>(V, G, sinit, zc, Xcur, B, NUMV, NUMV);
    qp_update<<<B, 256, 0, stream>>>(Xcur, Xprev, NO, lam, ssamp,
                                     p_smax, p_smin, p_sdmax, p_sdmin,
                                     p_sddmax, p_sddmin, V, out, B, it);
    float* t = Xcur; Xcur = Xprev; Xprev = t;
  }
  accum_out<<<B / 256, 256, 0, stream>>>(out, B);
}

// Round 5
// 476.633 us; speedup vs baseline: 3.9223x; 1.3771x over previous
//
#include <hip/hip_runtime.h>
#include <cstddef>

// learned_qp_solver: B=4096, NUM=256, NC=1530, IND=260, H=1024, OUT=1786, 5 iters.
//
// Structure exploited:
//   A_control = [I; -I; Pd; -Pd; Pdd; -Pdd]       (diff stencils / T, /T^2)
//   cost      = 3I + 2 Pd^T Pd + 2 Pdd^T Pdd      -> pentadiagonal SPD
//   KKT solve closed form:  x = G v + (b_eq/z0) z,  G = C^{-1} - z z^T / z0
//   -> per-iteration solve is a 4096x256x256 GEMM, rest is row-local stencils.
//   Cholesky tables of the pentadiagonal cost are COMPILE-TIME constants
//   (constexpr Newton sqrt) -> no serial setup kernel on device.
//
// ws layout (bytes), ~46.9 MB total:
//   [0,          29360128)  NO    fp32 [B][1792]   neural_out (stride-padded)
//   [29360128,   46137344)  h     fp32 [B][1024]   dead after GEMM2, reused as:
//        V @ +0, Xa @ +4MB, Xb @ +8MB, lam @ +12MB   (each fp32 [B][256])
//   [46137344,   46399488)  G     fp32 [256][256]
//   [46399488,   46400512)  zc    fp32 [256]
//   [46400512,   46924800)  Wtmp  fp64 [256][256]  G-build scratch

#define NUMV 256
#define QP_ITERS 5
#define NO_LD 1792

// ---------------- compile-time pentadiagonal Cholesky tables ----------------
struct FacT {
  double invd[256];
  double l1[257];
  double l2[258];
  double z[256];
  float  zcf[256];
};

constexpr double csqrt_(double x) {
  double g = (x > 1.0) ? x : 1.0;
  for (int i = 0; i < 64; ++i) g = 0.5 * (g + x / g);
  return g;
}

constexpr FacT make_fac() {
  FacT f{};
  const double T = 0.05, a = 1.0 / (T * T), b2 = a * a;
  double c0[256] = {}, c1[255] = {}, c2[254] = {};
  double dd[256] = {}, l1[256] = {}, l2[256] = {};
  for (int j = 0; j < 256; j++) {
    double cd1 = (j == 0 || j == 255) ? 1.0 : 2.0;
    double cd2 = (j == 0 || j == 255) ? 1.0 : ((j == 1 || j == 254) ? 5.0 : 6.0);
    c0[j] = 3.0 + 2.0 * a * cd1 + 2.0 * b2 * cd2;
  }
  for (int j = 0; j < 255; j++) c1[j] = -2.0 * a + 2.0 * b2 * ((j == 0 || j == 254) ? -2.0 : -4.0);
  for (int j = 0; j < 254; j++) c2[j] = 2.0 * b2;
  dd[0] = csqrt_(c0[0]); l1[0] = 0.0; l2[0] = 0.0;
  l1[1] = c1[0] / dd[0]; l2[1] = 0.0;
  dd[1] = csqrt_(c0[1] - l1[1] * l1[1]);
  for (int j = 2; j < 256; j++) {
    l2[j] = c2[j - 2] / dd[j - 2];
    l1[j] = (c1[j - 1] - l2[j] * l1[j - 1]) / dd[j - 1];
    dd[j] = csqrt_(c0[j] - l1[j] * l1[j] - l2[j] * l2[j]);
  }
  for (int j = 0; j < 256; j++) f.invd[j] = 1.0 / dd[j];
  for (int j = 0; j < 256; j++) f.l1[j] = l1[j];
  f.l1[256] = 0.0;
  for (int j = 0; j < 256; j++) f.l2[j] = l2[j];
  f.l2[256] = 0.0; f.l2[257] = 0.0;
  double w[256] = {}, zz[256] = {};
  w[0] = 1.0 / dd[0];
  w[1] = (-l1[1] * w[0]) / dd[1];
  for (int j = 2; j < 256; j++) w[j] = (-l1[j] * w[j - 1] - l2[j] * w[j - 2]) / dd[j];
  zz[255] = w[255] / dd[255];
  zz[254] = (w[254] - l1[255] * zz[255]) / dd[254];
  for (int j = 253; j >= 0; j--)
    zz[j] = (w[j] - l1[j + 1] * zz[j + 1] - l2[j + 2] * zz[j + 2]) / dd[j];
  for (int j = 0; j < 256; j++) f.z[j] = zz[j];
  for (int j = 0; j < 256; j++) f.zcf[j] = (float)(zz[j] / zz[0]);
  return f;
}

constexpr FacT FAC_HOST = make_fac();
__constant__ FacT FAC = FAC_HOST;

// ---------------- fp32 tiled GEMM (128x128x16, 256 thr, 8x8/thread) ----------------
// A [M][K] (rows 16B-aligned: K%4==0), Bw [K][ldb], C [M][ldc]; col-guarded by Nv.
template<bool RELU>
__global__ __launch_bounds__(256) void mlp_gemm128(
    const float* __restrict__ A, const float* __restrict__ Bw,
    const float* __restrict__ bias, float* __restrict__ C,
    int M, int Nv, int K, int ldb, int ldc)
{
  __shared__ float As[16][132];
  __shared__ float Bs[16][132];
  const int tid = threadIdx.x;
  const int tx = tid & 15, ty = tid >> 4;
  const int m0 = blockIdx.x * 128, n0 = blockIdx.y * 128;
  const bool b4 = (ldb & 3) == 0;
  float acc[8][8] = {};
  for (int k0 = 0; k0 < K; k0 += 16) {
    // ---- stage A (transpose to k-major) ----
#pragma unroll
    for (int q = 0; q < 2; q++) {
      const int fA = tid * 2 + q;
      const int row = fA >> 2;           // 0..127
      const int quad = fA & 3;           // 0..3
      const int k = k0 + quad * 4;
      float4 v = make_float4(0.f, 0.f, 0.f, 0.f);
      const float* src = &A[(size_t)(m0 + row) * K + k];
      if (k + 3 < K) {
        v = *reinterpret_cast<const float4*>(src);
      } else {
        if (k + 0 < K) v.x = src[0];
        if (k + 1 < K) v.y = src[1];
        if (k + 2 < K) v.z = src[2];
        if (k + 3 < K) v.w = src[3];
      }
      As[quad * 4 + 0][row] = v.x;
      As[quad * 4 + 1][row] = v.y;
      As[quad * 4 + 2][row] = v.z;
      As[quad * 4 + 3][row] = v.w;
    }
    // ---- stage B ----
#pragma unroll
    for (int q = 0; q < 2; q++) {
      const int fB = tid * 2 + q;
      const int krow = fB >> 5;          // 0..15
      const int col = (fB & 31) * 4;     // 0..124
      const int k = k0 + krow;
      const int n = n0 + col;
      float4 v = make_float4(0.f, 0.f, 0.f, 0.f);
      if (k < K) {
        const float* src = &Bw[(size_t)k * ldb + n];
        if (b4) {
          if (n + 3 < Nv) v = *reinterpret_cast<const float4*>(src);
          else {
            if (n + 0 < Nv) v.x = src[0];
            if (n + 1 < Nv) v.y = src[1];
            if (n + 2 < Nv) v.z = src[2];
            if (n + 3 < Nv) v.w = src[3];
          }
        } else {
          // ldb even, n even -> float2 accesses are 8B-aligned
          if (n + 1 < Nv) { float2 p = *reinterpret_cast<const float2*>(src); v.x = p.x; v.y = p.y; }
          else if (n < Nv) v.x = src[0];
          if (n + 3 < Nv) { float2 p = *reinterpret_cast<const float2*>(src + 2); v.z = p.x; v.w = p.y; }
          else if (n + 2 < Nv) v.z = src[2];
        }
      }
      *reinterpret_cast<float4*>(&Bs[krow][col]) = v;
    }
    __syncthreads();
#pragma unroll
    for (int kk = 0; kk < 16; kk++) {
      float4 a0 = *reinterpret_cast<const float4*>(&As[kk][ty * 4]);
      float4 a1 = *reinterpret_cast<const float4*>(&As[kk][64 + ty * 4]);
      float4 b0 = *reinterpret_cast<const float4*>(&Bs[kk][tx * 4]);
      float4 b1 = *reinterpret_cast<const float4*>(&Bs[kk][64 + tx * 4]);
      const float av[8] = {a0.x, a0.y, a0.z, a0.w, a1.x, a1.y, a1.z, a1.w};
      const float bv[8] = {b0.x, b0.y, b0.z, b0.w, b1.x, b1.y, b1.z, b1.w};
#pragma unroll
      for (int i = 0; i < 8; i++)
#pragma unroll
        for (int j = 0; j < 8; j++)
          acc[i][j] = fmaf(av[i], bv[j], acc[i][j]);
    }
    __syncthreads();
  }
  // ---- epilogue ----
#pragma unroll
  for (int rb = 0; rb < 2; rb++)
#pragma unroll
    for (int i = 0; i < 4; i++) {
      const int m = m0 + rb * 64 + ty * 4 + i;
#pragma unroll
      for (int cb = 0; cb < 2; cb++) {
        const int n = n0 + cb * 64 + tx * 4;
        float4 v;
        v.x = acc[rb * 4 + i][cb * 4 + 0]; v.y = acc[rb * 4 + i][cb * 4 + 1];
        v.z = acc[rb * 4 + i][cb * 4 + 2]; v.w = acc[rb * 4 + i][cb * 4 + 3];
        if (n + 3 < Nv) {
          v.x += bias[n]; v.y += bias[n + 1]; v.z += bias[n + 2]; v.w += bias[n + 3];
          if (RELU) {
            v.x = fmaxf(v.x, 0.f); v.y = fmaxf(v.y, 0.f);
            v.z = fmaxf(v.z, 0.f); v.w = fmaxf(v.w, 0.f);
          }
          *reinterpret_cast<float4*>(&C[(size_t)m * ldc + n]) = v;
        } else {
          float vv[4] = {v.x, v.y, v.z, v.w};
          for (int e = 0; e < 4; e++)
            if (n + e < Nv) {
              float t = vv[e] + bias[n + e];
              if (RELU) t = fmaxf(t, 0.f);
              C[(size_t)m * ldc + n + e] = t;
            }
        }
      }
    }
}

// ---- solve GEMM: X[m][n] = sum_k V[m][k] G[k][n] + beq[m]*zc[n]  (dims tile-exact)
__global__ __launch_bounds__(256) void gemm_solve(
    const float* __restrict__ V, const float* __restrict__ G,
    const float* __restrict__ beq, const float* __restrict__ zc,
    float* __restrict__ X, int M, int N, int K)
{
  __shared__ float As[16][68];
  __shared__ float Bs[16][68];
  const int tid = threadIdx.x;
  const int ty = tid >> 4, tx = tid & 15;
  const int m0 = blockIdx.x * 64, n0 = blockIdx.y * 64;
  const int lm = tid >> 2, lk = (tid & 3) * 4;
  const int lbk = tid >> 4, lbn = (tid & 15) * 4;
  float acc[4][4] = {};
  for (int k0 = 0; k0 < K; k0 += 16) {
    float4 av = *reinterpret_cast<const float4*>(&V[(size_t)(m0 + lm) * K + k0 + lk]);
    As[lk + 0][lm] = av.x; As[lk + 1][lm] = av.y;
    As[lk + 2][lm] = av.z; As[lk + 3][lm] = av.w;
    *reinterpret_cast<float4*>(&Bs[lbk][lbn]) =
        *reinterpret_cast<const float4*>(&G[(size_t)(k0 + lbk) * N + n0 + lbn]);
    __syncthreads();
#pragma unroll
    for (int kk = 0; kk < 16; kk++) {
      float4 a4 = *reinterpret_cast<const float4*>(&As[kk][ty * 4]);
      float4 b4 = *reinterpret_cast<const float4*>(&Bs[kk][tx * 4]);
      const float av2[4] = {a4.x, a4.y, a4.z, a4.w};
      const float bv2[4] = {b4.x, b4.y, b4.z, b4.w};
#pragma unroll
      for (int i = 0; i < 4; i++)
#pragma unroll
        for (int j = 0; j < 4; j++) acc[i][j] = fmaf(av2[i], bv2[j], acc[i][j]);
    }
    __syncthreads();
  }
#pragma unroll
  for (int i = 0; i < 4; i++) {
    const int m = m0 + ty * 4 + i;
    const float be = beq[m];
#pragma unroll
    for (int j = 0; j < 4; j++) {
      const int n = n0 + tx * 4 + j;
      X[(size_t)m * N + n] = acc[i][j] + be * zc[n];
    }
  }
}

// ---------------- build G = C^{-1} - z z^T/z0 (fp32), one column per thread ------
__global__ __launch_bounds__(256) void build_g(
    double* __restrict__ Wtmp, float* __restrict__ G, float* __restrict__ zc)
{
  const int t = threadIdx.x;
  double w1 = 0.0, w2 = 0.0;
#pragma unroll 4
  for (int j = 0; j < 256; j++) {
    double rhs = (j == t) ? 1.0 : 0.0;
    double wj = (rhs - FAC.l1[j] * w1 - FAC.l2[j] * w2) * FAC.invd[j];
    Wtmp[(size_t)j * 256 + t] = wj;
    w2 = w1; w1 = wj;
  }
  const double zr = FAC.z[t] / FAC.z[0];
  double y1 = 0.0, y2 = 0.0;
#pragma unroll 4
  for (int j = 255; j >= 0; j--) {
    double yj = (Wtmp[(size_t)j * 256 + t] - FAC.l1[j + 1] * y1 - FAC.l2[j + 2] * y2) * FAC.invd[j];
    G[(size_t)j * 256 + t] = (float)(yj - FAC.z[j] * zr);
    y2 = y1; y1 = yj;
  }
  zc[t] = FAC.zcf[t];
}

// ---------------- initial rhs V0 = lam0 + ss + b_aug0 @ A_control ----------------
__global__ __launch_bounds__(256) void init_v(
    const float* __restrict__ NO, const float* __restrict__ ss,
    const float* __restrict__ p_smax, const float* __restrict__ p_smin,
    const float* __restrict__ p_sdmax, const float* __restrict__ p_sdmin,
    const float* __restrict__ p_sddmax, const float* __restrict__ p_sddmin,
    float* __restrict__ V, int B)
{
  __shared__ float d1s[258], d2s[258];
  const int r = blockIdx.x, j = threadIdx.x;
  const float K0 = *p_smax + *p_smin, K1 = *p_sdmax + *p_sdmin, K2 = *p_sddmax + *p_sddmin;
  const float invT = 20.f, invT2 = 400.f;
  const float* no = NO + (size_t)r * NO_LD;
  float s1 = fmaxf(0.f, no[256 + j]), s2 = fmaxf(0.f, no[512 + j]);
  float D0 = K0 - s1 + s2;
  float D1 = 0.f, D2 = 0.f;
  if (j < 255) D1 = K1 - fmaxf(0.f, no[768 + j]) + fmaxf(0.f, no[1023 + j]);
  if (j < 254) D2 = K2 - fmaxf(0.f, no[1278 + j]) + fmaxf(0.f, no[1532 + j]);
  d1s[2 + j] = D1; d2s[2 + j] = D2;
  if (j < 2) { d1s[j] = 0.f; d2s[j] = 0.f; }
  __syncthreads();
  float qn = D0 + (d1s[j + 1] - d1s[j + 2]) * invT
                + (d2s[j] - 2.f * d2s[j + 1] + d2s[j + 2]) * invT2;
  V[(size_t)r * NUMV + j] = no[j] + ss[(size_t)r * NUMV + j] + qn;
}

// ---------------- per-iteration update: one block per row ----------------
__global__ __launch_bounds__(256) void qp_update(
    const float* __restrict__ X, const float* __restrict__ Xp,
    const float* __restrict__ NO, float* lam,
    const float* __restrict__ ss,
    const float* __restrict__ p_smax, const float* __restrict__ p_smin,
    const float* __restrict__ p_sdmax, const float* __restrict__ p_sdmin,
    const float* __restrict__ p_sddmax, const float* __restrict__ p_sddmin,
    float* __restrict__ Vn, float* __restrict__ out, int B, int it)
{
  __shared__ float xs[258], xps[258];
  __shared__ float e1s[258], e2s[258], d1s[258], d2s[258];
  __shared__ double red[3][4];
  const int r = blockIdx.x, j = threadIdx.x;
  const float smax = *p_smax, smin = *p_smin;
  const float sdmax = *p_sdmax, sdmin = *p_sdmin;
  const float sddmax = *p_sddmax, sddmin = *p_sddmin;
  const float invT = 20.f, invT2 = 400.f;

  const float x0 = X[(size_t)r * NUMV + j];
  xs[j] = x0;
  if (j < 2) xs[256 + j] = 0.f;
  float xp0 = 0.f;
  if (it > 0) {
    xp0 = Xp[(size_t)r * NUMV + j];
    xps[j] = xp0;
    if (j < 2) xps[256 + j] = 0.f;
  }
  __syncthreads();

  const bool h1 = j < 255, h2 = j < 254;
  const float x1 = xs[j + 1], x2 = xs[j + 2];
  const float v = (x1 - x0) * invT;
  const float aa = (x2 - 2.f * x1 + x0) * invT2;

  float rv0a = fmaxf(0.f, x0 - smax), rv0b = fmaxf(0.f, smin - x0);
  float rv1a = 0.f, rv1b = 0.f, rv2a = 0.f, rv2b = 0.f;
  float E1 = 0.f, E2 = 0.f;
  const float E0 = rv0a - rv0b;
  if (h1) { rv1a = fmaxf(0.f, v - sdmax); rv1b = fmaxf(0.f, sdmin - v); E1 = rv1a - rv1b; }
  if (h2) { rv2a = fmaxf(0.f, aa - sddmax); rv2b = fmaxf(0.f, sddmin - aa); E2 = rv2a - rv2b; }
  double res2 = (double)(rv0a * rv0a + rv0b * rv0b + rv1a * rv1a + rv1b * rv1b
                       + rv2a * rv2a + rv2b * rv2b);

  const float sn0a = fmaxf(0.f, smax - x0), sn0b = fmaxf(0.f, x0 - smin);
  float sn1a = 0.f, sn1b = 0.f, sn2a = 0.f, sn2b = 0.f;
  if (h1) { sn1a = fmaxf(0.f, sdmax - v); sn1b = fmaxf(0.f, v - sdmin); }
  if (h2) { sn2a = fmaxf(0.f, sddmax - aa); sn2b = fmaxf(0.f, aa - sddmin); }

  const float D0n = fminf(smax, x0) + fmaxf(smin, x0);
  const float D1n = h1 ? (fminf(sdmax, v) + fmaxf(sdmin, v)) : 0.f;
  const float D2n = h2 ? (fminf(sddmax, aa) + fmaxf(sddmin, aa)) : 0.f;

  float sp0a, sp0b, sp1a = 0.f, sp1b = 0.f, sp2a = 0.f, sp2b = 0.f;
  if (it == 0) {
    const float* no = NO + (size_t)r * NO_LD;
    sp0a = fmaxf(0.f, no[256 + j]); sp0b = fmaxf(0.f, no[512 + j]);
    if (h1) { sp1a = fmaxf(0.f, no[768 + j]); sp1b = fmaxf(0.f, no[1023 + j]); }
    if (h2) { sp2a = fmaxf(0.f, no[1278 + j]); sp2b = fmaxf(0.f, no[1532 + j]); }
  } else {
    const float xp1 = xps[j + 1], xp2 = xps[j + 2];
    const float vp = (xp1 - xp0) * invT;
    const float ap = (xp2 - 2.f * xp1 + xp0) * invT2;
    sp0a = fmaxf(0.f, smax - xp0); sp0b = fmaxf(0.f, xp0 - smin);
    if (h1) { sp1a = fmaxf(0.f, sdmax - vp); sp1b = fmaxf(0.f, vp - sdmin); }
    if (h2) { sp2a = fmaxf(0.f, sddmax - ap); sp2b = fmaxf(0.f, ap - sddmin); }
  }
  const float d0a = sp0a - sn0a, d0b = sp0b - sn0b;
  const float d1a = sp1a - sn1a, d1b = sp1b - sn1b;
  const float d2a = sp2a - sn2a, d2b = sp2b - sn2b;
  double fps2 = (double)(d0a * d0a + d0b * d0b + d1a * d1a + d1b * d1b
                       + d2a * d2a + d2b * d2b);

  e1s[2 + j] = E1; e2s[2 + j] = E2; d1s[2 + j] = D1n; d2s[2 + j] = D2n;
  if (j < 2) { e1s[j] = 0.f; e2s[j] = 0.f; d1s[j] = 0.f; d2s[j] = 0.f; }
  __syncthreads();

  const float lamj = (it == 0) ? NO[(size_t)r * NO_LD + j] : lam[(size_t)r * NUMV + j];
  const float lnew = lamj - (E0 + (e1s[j + 1] - e1s[j + 2]) * invT
                                + (e2s[j] - 2.f * e2s[j + 1] + e2s[j + 2]) * invT2);
  const float dl = lamj - lnew;
  double fpl2 = (double)(dl * dl);
  lam[(size_t)r * NUMV + j] = lnew;

  const size_t primOff = (size_t)B * NUMV;
  const size_t fpOff = primOff + (size_t)QP_ITERS * B;
  if (it < QP_ITERS - 1) {
    float qn = D0n + (d1s[j + 1] - d1s[j + 2]) * invT
                   + (d2s[j] - 2.f * d2s[j + 1] + d2s[j + 2]) * invT2;
    Vn[(size_t)r * NUMV + j] = lnew + ss[(size_t)r * NUMV + j] + qn;
  } else {
    out[(size_t)r * NUMV + j] = x0;
  }

  for (int o = 32; o > 0; o >>= 1) {
    res2 += __shfl_down(res2, o);
    fps2 += __shfl_down(fps2, o);
    fpl2 += __shfl_down(fpl2, o);
  }
  const int wid = j >> 6, lane = j & 63;
  if (lane == 0) { red[0][wid] = res2; red[1][wid] = fps2; red[2][wid] = fpl2; }
  __syncthreads();
  if (j == 0) {
    double r2 = red[0][0] + red[0][1] + red[0][2] + red[0][3];
    double s2_ = red[1][0] + red[1][1] + red[1][2] + red[1][3];
    double l2_ = red[2][0] + red[2][1] + red[2][2] + red[2][3];
    out[primOff + (size_t)it * B + r] = sqrtf((float)r2);
    out[fpOff + (size_t)it * B + r] = sqrtf((float)s2_) + sqrtf((float)l2_);
  }
}

// ---------------- final acc_primal / acc_fixed ----------------
__global__ __launch_bounds__(256) void accum_out(float* __restrict__ out, int B)
{
  const int r = blockIdx.x * 256 + threadIdx.x;
  const size_t primOff = (size_t)B * NUMV;
  const size_t fpOff = primOff + (size_t)QP_ITERS * B;
  const size_t accPOff = fpOff + (size_t)QP_ITERS * B;
  const size_t accFOff = accPOff + (size_t)B;
  float sp = 0.f, sf = 0.f;
  for (int it = 0; it < QP_ITERS; it++) {
    sp += out[primOff + (size_t)it * B + r];
    sf += out[fpOff + (size_t)it * B + r];
  }
  out[accPOff + r] = sp * (1.f / QP_ITERS);
  out[accFOff + r] = sf * (1.f / QP_ITERS);
}

extern "C" void kernel_launch(void* const* d_in, const int* in_sizes, int n_in,
                              void* d_out, int out_size, void* d_ws, size_t ws_size,
                              hipStream_t stream)
{
  const float* inp = (const float*)d_in[0];       // [B][260]
  const float* sinit = (const float*)d_in[1];     // [B][1]
  const float* ssamp = (const float*)d_in[2];     // [B][256]
  const float* p_smax = (const float*)d_in[3];
  const float* p_smin = (const float*)d_in[4];
  const float* p_sdmax = (const float*)d_in[5];
  const float* p_sdmin = (const float*)d_in[6];
  const float* p_sddmax = (const float*)d_in[7];
  const float* p_sddmin = (const float*)d_in[8];
  const float* W1 = (const float*)d_in[11];       // [260][1024]
  const float* b1 = (const float*)d_in[12];       // [1024]
  const float* W2 = (const float*)d_in[13];       // [1024][1786]
  const float* b2 = (const float*)d_in[14];       // [1786]
  float* out = (float*)d_out;

  const int B = in_sizes[1];                      // 4096
  const int IND = in_sizes[9];                    // 260
  const int H = in_sizes[12];                     // 1024
  const int OUTN = in_sizes[14];                  // 1786

  char* ws = (char*)d_ws;
  float* NO = (float*)ws;                                     // [B][NO_LD]
  char* hreg = ws + (size_t)B * NO_LD * 4;                    // 29,360,128
  float* h = (float*)hreg;                                    // [B][1024]
  float* V = (float*)hreg;
  float* Xa = (float*)(hreg + (size_t)B * NUMV * 4);
  float* Xb = (float*)(hreg + (size_t)2 * B * NUMV * 4);
  float* lam = (float*)(hreg + (size_t)3 * B * NUMV * 4);
  char* after_h = hreg + (size_t)B * H * 4;                   // 46,137,344
  float* G = (float*)after_h;                                 // [256][256] fp32
  float* zc = (float*)(after_h + 262144);                     // [256]
  double* Wtmp = (double*)(after_h + 262144 + 1024);          // [256][256] fp64

  build_g<<<1, 256, 0, stream>>>(Wtmp, G, zc);
  {
    dim3 g(B / 128, H / 128);
    mlp_gemm128<true><<<g, 256, 0, stream>>>(inp, W1, b1, h, B, H, IND, H, H);
  }
  {
    dim3 g(B / 128, (OUTN + 127) / 128);
    mlp_gemm128<false><<<g, 256, 0, stream>>>(h, W2, b2, NO, B, OUTN, H, OUTN, NO_LD);
  }
  init_v<<<B, 256, 0, stream>>>(NO, ssamp, p_smax, p_smin, p_sdmax, p_sdmin,
                                p_sddmax, p_sddmin, V, B);
  float* Xcur = Xa;
  float* Xprev = Xb;
  for (int it = 0; it < QP_ITERS; it++) {
    dim3 g(B / 64, NUMV / 64);
    gemm_solve<<<g, 256, 0, stream>>>(V, G, sinit, zc, Xcur, B, NUMV, NUMV);
    qp_update<<<B, 256, 0, stream>>>(Xcur, Xprev, NO, lam, ssamp,
                                     p_smax, p_smin, p_sdmax, p_sdmin,
                                     p_sddmax, p_sddmin, V, out, B, it);
    float* t = Xcur; Xcur = Xprev; Xprev = t;
  }
  accum_out<<<B / 256, 256, 0, stream>>>(out, B);
}

// Round 6
// 303.794 us; speedup vs baseline: 6.1539x; 1.5689x over previous
//
#include <hip/hip_runtime.h>
#include <cstddef>

// learned_qp_solver: B=4096, NUM=256, NC=1530, IND=260, H=1024, OUT=1786, 5 iters.
//
//   KKT solve closed form:  x = G v + (b_eq/z0) z,  G = C^{-1} - z z^T / z0
//   MLP GEMMs on matrix cores: fp16 inputs (11-bit mantissa), fp32 MFMA accum,
//   classic v_mfma_f32_16x16x16_f16 (layout: A row=lane&15,k=4*(lane>>4)+j;
//   D col=lane&15,row=4*(lane>>4)+reg).  Weights pre-transposed to [N][K] fp16.
//
// ws layout (bytes), ~46.9 MB:
//   [0,          29360128)  NO   fp32 [B][1792]
//   [29360128,   37748736)  h    fp16 [B][1024]  (dead after GEMM2) -> V, Xa reuse
//   [37748736,   41943040)  Xb   fp32 [B][256]
//   [41943040,   45600768)  W2T  fp16 [1786][1024] (dead after GEMM2) -> lam reuse
//   [46137344,   46399488)  G    fp32 [256][256]
//   [46399488,   46400512)  zc   fp32 [256]
//   [46400512,   46932992)  Wtmp fp64 (build_g only) / W1T fp16 [1024][260]

#define NUMV 256
#define QP_ITERS 5
#define NO_LD 1792

typedef _Float16 f16x4 __attribute__((ext_vector_type(4)));
typedef float f32x4 __attribute__((ext_vector_type(4)));

// ---------------- compile-time pentadiagonal Cholesky tables ----------------
struct FacT {
  double invd[256];
  double l1[257];
  double l2[258];
  double z[256];
  float  zcf[256];
};

constexpr double csqrt_(double x) {
  double g = (x > 1.0) ? x : 1.0;
  for (int i = 0; i < 64; ++i) g = 0.5 * (g + x / g);
  return g;
}

constexpr FacT make_fac() {
  FacT f{};
  const double T = 0.05, a = 1.0 / (T * T), b2 = a * a;
  double c0[256] = {}, c1[255] = {}, c2[254] = {};
  double dd[256] = {}, l1[256] = {}, l2[256] = {};
  for (int j = 0; j < 256; j++) {
    double cd1 = (j == 0 || j == 255) ? 1.0 : 2.0;
    double cd2 = (j == 0 || j == 255) ? 1.0 : ((j == 1 || j == 254) ? 5.0 : 6.0);
    c0[j] = 3.0 + 2.0 * a * cd1 + 2.0 * b2 * cd2;
  }
  for (int j = 0; j < 255; j++) c1[j] = -2.0 * a + 2.0 * b2 * ((j == 0 || j == 254) ? -2.0 : -4.0);
  for (int j = 0; j < 254; j++) c2[j] = 2.0 * b2;
  dd[0] = csqrt_(c0[0]); l1[0] = 0.0; l2[0] = 0.0;
  l1[1] = c1[0] / dd[0]; l2[1] = 0.0;
  dd[1] = csqrt_(c0[1] - l1[1] * l1[1]);
  for (int j = 2; j < 256; j++) {
    l2[j] = c2[j - 2] / dd[j - 2];
    l1[j] = (c1[j - 1] - l2[j] * l1[j - 1]) / dd[j - 1];
    dd[j] = csqrt_(c0[j] - l1[j] * l1[j] - l2[j] * l2[j]);
  }
  for (int j = 0; j < 256; j++) f.invd[j] = 1.0 / dd[j];
  for (int j = 0; j < 256; j++) f.l1[j] = l1[j];
  f.l1[256] = 0.0;
  for (int j = 0; j < 256; j++) f.l2[j] = l2[j];
  f.l2[256] = 0.0; f.l2[257] = 0.0;
  double w[256] = {}, zz[256] = {};
  w[0] = 1.0 / dd[0];
  w[1] = (-l1[1] * w[0]) / dd[1];
  for (int j = 2; j < 256; j++) w[j] = (-l1[j] * w[j - 1] - l2[j] * w[j - 2]) / dd[j];
  zz[255] = w[255] / dd[255];
  zz[254] = (w[254] - l1[255] * zz[255]) / dd[254];
  for (int j = 253; j >= 0; j--)
    zz[j] = (w[j] - l1[j + 1] * zz[j + 1] - l2[j + 2] * zz[j + 2]) / dd[j];
  for (int j = 0; j < 256; j++) f.z[j] = zz[j];
  for (int j = 0; j < 256; j++) f.zcf[j] = (float)(zz[j] / zz[0]);
  return f;
}

constexpr FacT FAC_HOST = make_fac();
__constant__ FacT FAC = FAC_HOST;

// ---------------- transpose + fp32->fp16 convert: in [K][N] -> out [N][K] ----------------
__global__ __launch_bounds__(256) void transpose_cvt(
    const float* __restrict__ in, _Float16* __restrict__ out, int K, int N)
{
  __shared__ float t[32][33];
  const int bk = blockIdx.x * 32, bn = blockIdx.y * 32;
  const int x = threadIdx.x, y = threadIdx.y;
  for (int yy = y; yy < 32; yy += 8) {
    const int k = bk + yy, n = bn + x;
    t[yy][x] = (k < K && n < N) ? in[(size_t)k * N + n] : 0.f;
  }
  __syncthreads();
  for (int yy = y; yy < 32; yy += 8) {
    const int n = bn + yy, k = bk + x;
    if (n < N && k < K) out[(size_t)n * K + k] = (_Float16)t[x][yy];
  }
}

// ---------------- MFMA GEMM: C = A * Bt^T + bias, tile 128x128, 4 waves ----------------
// A: [M][lda] fp32 (A_FP32) or fp16;  Bt: [N][ldk] fp16 (pre-transposed weights)
// OUT_H16: C fp16 with relu (h);  else C fp32 strided (NO), col-guarded by Nv.
template<bool A_FP32, bool OUT_H16>
__global__ __launch_bounds__(256) void mfma_gemm(
    const void* __restrict__ Av, const _Float16* __restrict__ Bt,
    const float* __restrict__ bias, void* __restrict__ Cv,
    int M, int Nv, int K, int lda, int ldk, int ldc)
{
  __shared__ _Float16 At[128][36];
  __shared__ _Float16 Bs[128][36];
  const int tid = threadIdx.x;
  const int lane = tid & 63, wid = tid >> 6;
  const int wr = wid >> 1, wc = wid & 1;        // wave -> 64x64 quadrant
  const int lrow = lane & 15, lb = lane >> 4;
  const int m0 = blockIdx.x * 128, n0 = blockIdx.y * 128;
  const int srow = tid >> 1, skh = (tid & 1) * 16;

  f32x4 acc[4][4];
#pragma unroll
  for (int i = 0; i < 4; i++)
#pragma unroll
    for (int j = 0; j < 4; j++) acc[i][j] = (f32x4)0.0f;

  const int nsteps = (K + 31) / 32;
  for (int t = 0; t < nsteps; ++t) {
    const int k0 = t * 32;
    // ---- stage A tile [128 rows][32 k] ----
    if (A_FP32) {
      const float* A = (const float*)Av;
#pragma unroll
      for (int i = 0; i < 4; i++) {
        const int k = k0 + skh + i * 4;
        f16x4 hv = {};
        if (k + 4 <= K) {
          const float4 v = *reinterpret_cast<const float4*>(&A[(size_t)(m0 + srow) * lda + k]);
          hv[0] = (_Float16)v.x; hv[1] = (_Float16)v.y;
          hv[2] = (_Float16)v.z; hv[3] = (_Float16)v.w;
        }
        *reinterpret_cast<f16x4*>(&At[srow][skh + i * 4]) = hv;
      }
    } else {
      const _Float16* A = (const _Float16*)Av;
#pragma unroll
      for (int i = 0; i < 4; i++) {
        const int k = k0 + skh + i * 4;
        f16x4 hv = {};
        if (k + 4 <= K) hv = *reinterpret_cast<const f16x4*>(&A[(size_t)(m0 + srow) * lda + k]);
        *reinterpret_cast<f16x4*>(&At[srow][skh + i * 4]) = hv;
      }
    }
    // ---- stage B tile [128 cols][32 k] from W^T ----
    {
      const int n = n0 + srow;
#pragma unroll
      for (int i = 0; i < 4; i++) {
        const int k = k0 + skh + i * 4;
        f16x4 hv = {};
        if (n < Nv && k + 4 <= K)
          hv = *reinterpret_cast<const f16x4*>(&Bt[(size_t)n * ldk + k]);
        *reinterpret_cast<f16x4*>(&Bs[srow][skh + i * 4]) = hv;
      }
    }
    __syncthreads();
    // ---- 32 MFMAs per wave (2 k-halves x 4x4 fragments) ----
#pragma unroll
    for (int h = 0; h < 2; h++) {
      f16x4 af[4], bf[4];
#pragma unroll
      for (int i = 0; i < 4; i++)
        af[i] = *reinterpret_cast<const f16x4*>(&At[wr * 64 + i * 16 + lrow][h * 16 + lb * 4]);
#pragma unroll
      for (int j = 0; j < 4; j++)
        bf[j] = *reinterpret_cast<const f16x4*>(&Bs[wc * 64 + j * 16 + lrow][h * 16 + lb * 4]);
#pragma unroll
      for (int i = 0; i < 4; i++)
#pragma unroll
        for (int j = 0; j < 4; j++)
          acc[i][j] = __builtin_amdgcn_mfma_f32_16x16x16f16(af[i], bf[j], acc[i][j], 0, 0, 0);
    }
    __syncthreads();
  }
  // ---- epilogue: D col = lane&15, row = 4*(lane>>4)+reg ----
#pragma unroll
  for (int i = 0; i < 4; i++) {
#pragma unroll
    for (int j = 0; j < 4; j++) {
      const int gcol = n0 + wc * 64 + j * 16 + lrow;
      if (gcol < Nv) {
        const float bv = bias[gcol];
#pragma unroll
        for (int r = 0; r < 4; r++) {
          const int grow = m0 + wr * 64 + i * 16 + lb * 4 + r;
          float v = acc[i][j][r] + bv;
          if (OUT_H16) {
            v = fmaxf(v, 0.f);
            ((_Float16*)Cv)[(size_t)grow * ldc + gcol] = (_Float16)v;
          } else {
            ((float*)Cv)[(size_t)grow * ldc + gcol] = v;
          }
        }
      }
    }
  }
}

// ---- solve GEMM: X[m][n] = sum_k V[m][k] G[k][n] + beq[m]*zc[n]  (fp32, dims exact)
__global__ __launch_bounds__(256) void gemm_solve(
    const float* __restrict__ V, const float* __restrict__ G,
    const float* __restrict__ beq, const float* __restrict__ zc,
    float* __restrict__ X, int M, int N, int K)
{
  __shared__ float As[16][68];
  __shared__ float Bs[16][68];
  const int tid = threadIdx.x;
  const int ty = tid >> 4, tx = tid & 15;
  const int m0 = blockIdx.x * 64, n0 = blockIdx.y * 64;
  const int lm = tid >> 2, lk = (tid & 3) * 4;
  const int lbk = tid >> 4, lbn = (tid & 15) * 4;
  float acc[4][4] = {};
  for (int k0 = 0; k0 < K; k0 += 16) {
    float4 av = *reinterpret_cast<const float4*>(&V[(size_t)(m0 + lm) * K + k0 + lk]);
    As[lk + 0][lm] = av.x; As[lk + 1][lm] = av.y;
    As[lk + 2][lm] = av.z; As[lk + 3][lm] = av.w;
    *reinterpret_cast<float4*>(&Bs[lbk][lbn]) =
        *reinterpret_cast<const float4*>(&G[(size_t)(k0 + lbk) * N + n0 + lbn]);
    __syncthreads();
#pragma unroll
    for (int kk = 0; kk < 16; kk++) {
      float4 a4 = *reinterpret_cast<const float4*>(&As[kk][ty * 4]);
      float4 b4 = *reinterpret_cast<const float4*>(&Bs[kk][tx * 4]);
      const float av2[4] = {a4.x, a4.y, a4.z, a4.w};
      const float bv2[4] = {b4.x, b4.y, b4.z, b4.w};
#pragma unroll
      for (int i = 0; i < 4; i++)
#pragma unroll
        for (int j = 0; j < 4; j++) acc[i][j] = fmaf(av2[i], bv2[j], acc[i][j]);
    }
    __syncthreads();
  }
#pragma unroll
  for (int i = 0; i < 4; i++) {
    const int m = m0 + ty * 4 + i;
    const float be = beq[m];
#pragma unroll
    for (int j = 0; j < 4; j++) {
      const int n = n0 + tx * 4 + j;
      X[(size_t)m * N + n] = acc[i][j] + be * zc[n];
    }
  }
}

// ---------------- build G = C^{-1} - z z^T/z0 (fp32), one column per thread ------
__global__ __launch_bounds__(256) void build_g(
    double* __restrict__ Wtmp, float* __restrict__ G, float* __restrict__ zc)
{
  const int t = threadIdx.x;
  double w1 = 0.0, w2 = 0.0;
#pragma unroll 4
  for (int j = 0; j < 256; j++) {
    double rhs = (j == t) ? 1.0 : 0.0;
    double wj = (rhs - FAC.l1[j] * w1 - FAC.l2[j] * w2) * FAC.invd[j];
    Wtmp[(size_t)j * 256 + t] = wj;
    w2 = w1; w1 = wj;
  }
  const double zr = FAC.z[t] / FAC.z[0];
  double y1 = 0.0, y2 = 0.0;
#pragma unroll 4
  for (int j = 255; j >= 0; j--) {
    double yj = (Wtmp[(size_t)j * 256 + t] - FAC.l1[j + 1] * y1 - FAC.l2[j + 2] * y2) * FAC.invd[j];
    G[(size_t)j * 256 + t] = (float)(yj - FAC.z[j] * zr);
    y2 = y1; y1 = yj;
  }
  zc[t] = FAC.zcf[t];
}

// ---------------- initial rhs V0 = lam0 + ss + b_aug0 @ A_control ----------------
__global__ __launch_bounds__(256) void init_v(
    const float* __restrict__ NO, const float* __restrict__ ss,
    const float* __restrict__ p_smax, const float* __restrict__ p_smin,
    const float* __restrict__ p_sdmax, const float* __restrict__ p_sdmin,
    const float* __restrict__ p_sddmax, const float* __restrict__ p_sddmin,
    float* __restrict__ V, int B)
{
  __shared__ float d1s[258], d2s[258];
  const int r = blockIdx.x, j = threadIdx.x;
  const float K0 = *p_smax + *p_smin, K1 = *p_sdmax + *p_sdmin, K2 = *p_sddmax + *p_sddmin;
  const float invT = 20.f, invT2 = 400.f;
  const float* no = NO + (size_t)r * NO_LD;
  float s1 = fmaxf(0.f, no[256 + j]), s2 = fmaxf(0.f, no[512 + j]);
  float D0 = K0 - s1 + s2;
  float D1 = 0.f, D2 = 0.f;
  if (j < 255) D1 = K1 - fmaxf(0.f, no[768 + j]) + fmaxf(0.f, no[1023 + j]);
  if (j < 254) D2 = K2 - fmaxf(0.f, no[1278 + j]) + fmaxf(0.f, no[1532 + j]);
  d1s[2 + j] = D1; d2s[2 + j] = D2;
  if (j < 2) { d1s[j] = 0.f; d2s[j] = 0.f; }
  __syncthreads();
  float qn = D0 + (d1s[j + 1] - d1s[j + 2]) * invT
                + (d2s[j] - 2.f * d2s[j + 1] + d2s[j + 2]) * invT2;
  V[(size_t)r * NUMV + j] = no[j] + ss[(size_t)r * NUMV + j] + qn;
}

// ---------------- per-iteration update: one block per row ----------------
__global__ __launch_bounds__(256) void qp_update(
    const float* __restrict__ X, const float* __restrict__ Xp,
    const float* __restrict__ NO, float* lam,
    const float* __restrict__ ss,
    const float* __restrict__ p_smax, const float* __restrict__ p_smin,
    const float* __restrict__ p_sdmax, const float* __restrict__ p_sdmin,
    const float* __restrict__ p_sddmax, const float* __restrict__ p_sddmin,
    float* __restrict__ Vn, float* __restrict__ out, int B, int it)
{
  __shared__ float xs[258], xps[258];
  __shared__ float e1s[258], e2s[258], d1s[258], d2s[258];
  __shared__ double red[3][4];
  const int r = blockIdx.x, j = threadIdx.x;
  const float smax = *p_smax, smin = *p_smin;
  const float sdmax = *p_sdmax, sdmin = *p_sdmin;
  const float sddmax = *p_sddmax, sddmin = *p_sddmin;
  const float invT = 20.f, invT2 = 400.f;

  const float x0 = X[(size_t)r * NUMV + j];
  xs[j] = x0;
  if (j < 2) xs[256 + j] = 0.f;
  float xp0 = 0.f;
  if (it > 0) {
    xp0 = Xp[(size_t)r * NUMV + j];
    xps[j] = xp0;
    if (j < 2) xps[256 + j] = 0.f;
  }
  __syncthreads();

  const bool h1 = j < 255, h2 = j < 254;
  const float x1 = xs[j + 1], x2 = xs[j + 2];
  const float v = (x1 - x0) * invT;
  const float aa = (x2 - 2.f * x1 + x0) * invT2;

  float rv0a = fmaxf(0.f, x0 - smax), rv0b = fmaxf(0.f, smin - x0);
  float rv1a = 0.f, rv1b = 0.f, rv2a = 0.f, rv2b = 0.f;
  float E1 = 0.f, E2 = 0.f;
  const float E0 = rv0a - rv0b;
  if (h1) { rv1a = fmaxf(0.f, v - sdmax); rv1b = fmaxf(0.f, sdmin - v); E1 = rv1a - rv1b; }
  if (h2) { rv2a = fmaxf(0.f, aa - sddmax); rv2b = fmaxf(0.f, sddmin - aa); E2 = rv2a - rv2b; }
  double res2 = (double)(rv0a * rv0a + rv0b * rv0b + rv1a * rv1a + rv1b * rv1b
                       + rv2a * rv2a + rv2b * rv2b);

  const float sn0a = fmaxf(0.f, smax - x0), sn0b = fmaxf(0.f, x0 - smin);
  float sn1a = 0.f, sn1b = 0.f, sn2a = 0.f, sn2b = 0.f;
  if (h1) { sn1a = fmaxf(0.f, sdmax - v); sn1b = fmaxf(0.f, v - sdmin); }
  if (h2) { sn2a = fmaxf(0.f, sddmax - aa); sn2b = fmaxf(0.f, aa - sddmin); }

  const float D0n = fminf(smax, x0) + fmaxf(smin, x0);
  const float D1n = h1 ? (fminf(sdmax, v) + fmaxf(sdmin, v)) : 0.f;
  const float D2n = h2 ? (fminf(sddmax, aa) + fmaxf(sddmin, aa)) : 0.f;

  float sp0a, sp0b, sp1a = 0.f, sp1b = 0.f, sp2a = 0.f, sp2b = 0.f;
  if (it == 0) {
    const float* no = NO + (size_t)r * NO_LD;
    sp0a = fmaxf(0.f, no[256 + j]); sp0b = fmaxf(0.f, no[512 + j]);
    if (h1) { sp1a = fmaxf(0.f, no[768 + j]); sp1b = fmaxf(0.f, no[1023 + j]); }
    if (h2) { sp2a = fmaxf(0.f, no[1278 + j]); sp2b = fmaxf(0.f, no[1532 + j]); }
  } else {
    const float xp1 = xps[j + 1], xp2 = xps[j + 2];
    const float vp = (xp1 - xp0) * invT;
    const float ap = (xp2 - 2.f * xp1 + xp0) * invT2;
    sp0a = fmaxf(0.f, smax - xp0); sp0b = fmaxf(0.f, xp0 - smin);
    if (h1) { sp1a = fmaxf(0.f, sdmax - vp); sp1b = fmaxf(0.f, vp - sdmin); }
    if (h2) { sp2a = fmaxf(0.f, sddmax - ap); sp2b = fmaxf(0.f, ap - sddmin); }
  }
  const float d0a = sp0a - sn0a, d0b = sp0b - sn0b;
  const float d1a = sp1a - sn1a, d1b = sp1b - sn1b;
  const float d2a = sp2a - sn2a, d2b = sp2b - sn2b;
  double fps2 = (double)(d0a * d0a + d0b * d0b + d1a * d1a + d1b * d1b
                       + d2a * d2a + d2b * d2b);

  e1s[2 + j] = E1; e2s[2 + j] = E2; d1s[2 + j] = D1n; d2s[2 + j] = D2n;
  if (j < 2) { e1s[j] = 0.f; e2s[j] = 0.f; d1s[j] = 0.f; d2s[j] = 0.f; }
  __syncthreads();

  const float lamj = (it == 0) ? NO[(size_t)r * NO_LD + j] : lam[(size_t)r * NUMV + j];
  const float lnew = lamj - (E0 + (e1s[j + 1] - e1s[j + 2]) * invT
                                + (e2s[j] - 2.f * e2s[j + 1] + e2s[j + 2]) * invT2);
  const float dl = lamj - lnew;
  double fpl2 = (double)(dl * dl);
  lam[(size_t)r * NUMV + j] = lnew;

  const size_t primOff = (size_t)B * NUMV;
  const size_t fpOff = primOff + (size_t)QP_ITERS * B;
  if (it < QP_ITERS - 1) {
    float qn = D0n + (d1s[j + 1] - d1s[j + 2]) * invT
                   + (d2s[j] - 2.f * d2s[j + 1] + d2s[j + 2]) * invT2;
    Vn[(size_t)r * NUMV + j] = lnew + ss[(size_t)r * NUMV + j] + qn;
  } else {
    out[(size_t)r * NUMV + j] = x0;
  }

  for (int o = 32; o > 0; o >>= 1) {
    res2 += __shfl_down(res2, o);
    fps2 += __shfl_down(fps2, o);
    fpl2 += __shfl_down(fpl2, o);
  }
  const int wid = j >> 6, lane = j & 63;
  if (lane == 0) { red[0][wid] = res2; red[1][wid] = fps2; red[2][wid] = fpl2; }
  __syncthreads();
  if (j == 0) {
    double r2 = red[0][0] + red[0][1] + red[0][2] + red[0][3];
    double s2_ = red[1][0] + red[1][1] + red[1][2] + red[1][3];
    double l2_ = red[2][0] + red[2][1] + red[2][2] + red[2][3];
    out[primOff + (size_t)it * B + r] = sqrtf((float)r2);
    out[fpOff + (size_t)it * B + r] = sqrtf((float)s2_) + sqrtf((float)l2_);
  }
}

// ---------------- final acc_primal / acc_fixed ----------------
__global__ __launch_bounds__(256) void accum_out(float* __restrict__ out, int B)
{
  const int r = blockIdx.x * 256 + threadIdx.x;
  const size_t primOff = (size_t)B * NUMV;
  const size_t fpOff = primOff + (size_t)QP_ITERS * B;
  const size_t accPOff = fpOff + (size_t)QP_ITERS * B;
  const size_t accFOff = accPOff + (size_t)B;
  float sp = 0.f, sf = 0.f;
  for (int it = 0; it < QP_ITERS; it++) {
    sp += out[primOff + (size_t)it * B + r];
    sf += out[fpOff + (size_t)it * B + r];
  }
  out[accPOff + r] = sp * (1.f / QP_ITERS);
  out[accFOff + r] = sf * (1.f / QP_ITERS);
}

extern "C" void kernel_launch(void* const* d_in, const int* in_sizes, int n_in,
                              void* d_out, int out_size, void* d_ws, size_t ws_size,
                              hipStream_t stream)
{
  const float* inp = (const float*)d_in[0];       // [B][260]
  const float* sinit = (const float*)d_in[1];     // [B][1]
  const float* ssamp = (const float*)d_in[2];     // [B][256]
  const float* p_smax = (const float*)d_in[3];
  const float* p_smin = (const float*)d_in[4];
  const float* p_sdmax = (const float*)d_in[5];
  const float* p_sdmin = (const float*)d_in[6];
  const float* p_sddmax = (const float*)d_in[7];
  const float* p_sddmin = (const float*)d_in[8];
  const float* W1 = (const float*)d_in[11];       // [260][1024]
  const float* b1 = (const float*)d_in[12];       // [1024]
  const float* W2 = (const float*)d_in[13];       // [1024][1786]
  const float* b2 = (const float*)d_in[14];       // [1786]
  float* out = (float*)d_out;

  const int B = in_sizes[1];                      // 4096
  const int IND = in_sizes[9];                    // 260
  const int H = in_sizes[12];                     // 1024
  const int OUTN = in_sizes[14];                  // 1786

  char* ws = (char*)d_ws;
  float* NO = (float*)ws;                                      // [B][1792] fp32
  char* p = ws + (size_t)B * NO_LD * 4;                        // 29,360,128
  _Float16* hH = (_Float16*)p;                                 // [B][1024] fp16
  float* V  = (float*)p;                                       // reuse after GEMM2
  float* Xa = (float*)(p + (size_t)B * NUMV * 4);              // +4MB
  float* Xb = (float*)(p + (size_t)2 * B * NUMV * 4);          // +8MB
  char* q = p + (size_t)3 * B * NUMV * 4;                      // 41,943,040
  _Float16* W2T = (_Float16*)q;                                // [1786][1024] fp16
  float* lam = (float*)q;                                      // reuse after GEMM2
  char* r2 = q + (size_t)B * NUMV * 4;                         // 46,137,344
  float* G = (float*)r2;                                       // [256][256] fp32
  float* zc = (float*)(r2 + 262144);                           // [256]
  char* r3 = r2 + 263168;                                      // 46,400,512
  double* Wtmp = (double*)r3;                                  // build_g scratch
  _Float16* W1T = (_Float16*)r3;                               // [1024][260] fp16 (after build_g)

  build_g<<<1, 256, 0, stream>>>(Wtmp, G, zc);
  {
    dim3 g((IND + 31) / 32, (H + 31) / 32), blk(32, 8);
    transpose_cvt<<<g, blk, 0, stream>>>(W1, W1T, IND, H);
  }
  {
    dim3 g((H + 31) / 32, (OUTN + 31) / 32), blk(32, 8);
    transpose_cvt<<<g, blk, 0, stream>>>(W2, W2T, H, OUTN);
  }
  {
    dim3 g(B / 128, H / 128);
    mfma_gemm<true, true><<<g, 256, 0, stream>>>(inp, W1T, b1, hH, B, H, IND, IND, IND, H);
  }
  {
    dim3 g(B / 128, (OUTN + 127) / 128);
    mfma_gemm<false, false><<<g, 256, 0, stream>>>(hH, W2T, b2, NO, B, OUTN, H, H, H, NO_LD);
  }
  init_v<<<B, 256, 0, stream>>>(NO, ssamp, p_smax, p_smin, p_sdmax, p_sdmin,
                                p_sddmax, p_sddmin, V, B);
  float* Xcur = Xa;
  float* Xprev = Xb;
  for (int it = 0; it < QP_ITERS; it++) {
    dim3 g(B / 64, NUMV / 64);
    gemm_solve<<<g, 256, 0, stream>>>(V, G, sinit, zc, Xcur, B, NUMV, NUMV);
    qp_update<<<B, 256, 0, stream>>>(Xcur, Xprev, NO, lam, ssamp,
                                     p_smax, p_smin, p_sdmax, p_sdmin,
                                     p_sddmax, p_sddmin, V, out, B, it);
    float* t = Xcur; Xcur = Xprev; Xprev = t;
  }
  accum_out<<<B / 256, 256, 0, stream>>>(out, B);
}

// Round 7
// 296.001 us; speedup vs baseline: 6.3159x; 1.0263x over previous
//
#include <hip/hip_runtime.h>
#include <cstddef>

// learned_qp_solver: B=4096, NUM=256, NC=1530, IND=260, H=1024, OUT=1786, 5 iters.
//
//   KKT solve closed form:  x = G v + (b_eq/z0) z,  G = C^{-1} - z z^T / z0 (symmetric)
//   MLP on matrix cores (fp16 in / fp32 accum, v_mfma_f32_16x16x16_f16, 64x128 tiles).
//   ENTIRE 5-iteration QP loop is row-local given G -> single fused kernel qp_all:
//   512 blocks x 8 rows, state in LDS/regs, G streamed from L2 (256 KB, hot).
//
// ws layout (bytes):
//   [0,          29360128)  NO   fp32 [B][1792]
//   [29360128,   37748736)  h    fp16 [B][1024]
//   [37748736,   41406464)  W2T  fp16 [1786][1024]
//   [41406464,   41939456)  W1T  fp16 [1024][260]
//   [41939456,   42201600)  G    fp32 [256][256]
//   [42201600,   42202624)  zc   fp32 [256]

#define NUMV 256
#define QP_ITERS 5
#define NO_LD 1792
#define RPB 8

typedef _Float16 f16x4 __attribute__((ext_vector_type(4)));
typedef float f32x4 __attribute__((ext_vector_type(4)));

// ---------------- compile-time pentadiagonal Cholesky tables ----------------
struct FacT {
  double invd[256];
  double l1[257];
  double l2[258];
  double z[256];
  float  zcf[256];
};

constexpr double csqrt_(double x) {
  double g = (x > 1.0) ? x : 1.0;
  for (int i = 0; i < 64; ++i) g = 0.5 * (g + x / g);
  return g;
}

constexpr FacT make_fac() {
  FacT f{};
  const double T = 0.05, a = 1.0 / (T * T), b2 = a * a;
  double c0[256] = {}, c1[255] = {}, c2[254] = {};
  double dd[256] = {}, l1[256] = {}, l2[256] = {};
  for (int j = 0; j < 256; j++) {
    double cd1 = (j == 0 || j == 255) ? 1.0 : 2.0;
    double cd2 = (j == 0 || j == 255) ? 1.0 : ((j == 1 || j == 254) ? 5.0 : 6.0);
    c0[j] = 3.0 + 2.0 * a * cd1 + 2.0 * b2 * cd2;
  }
  for (int j = 0; j < 255; j++) c1[j] = -2.0 * a + 2.0 * b2 * ((j == 0 || j == 254) ? -2.0 : -4.0);
  for (int j = 0; j < 254; j++) c2[j] = 2.0 * b2;
  dd[0] = csqrt_(c0[0]); l1[0] = 0.0; l2[0] = 0.0;
  l1[1] = c1[0] / dd[0]; l2[1] = 0.0;
  dd[1] = csqrt_(c0[1] - l1[1] * l1[1]);
  for (int j = 2; j < 256; j++) {
    l2[j] = c2[j - 2] / dd[j - 2];
    l1[j] = (c1[j - 1] - l2[j] * l1[j - 1]) / dd[j - 1];
    dd[j] = csqrt_(c0[j] - l1[j] * l1[j] - l2[j] * l2[j]);
  }
  for (int j = 0; j < 256; j++) f.invd[j] = 1.0 / dd[j];
  for (int j = 0; j < 256; j++) f.l1[j] = l1[j];
  f.l1[256] = 0.0;
  for (int j = 0; j < 256; j++) f.l2[j] = l2[j];
  f.l2[256] = 0.0; f.l2[257] = 0.0;
  double w[256] = {}, zz[256] = {};
  w[0] = 1.0 / dd[0];
  w[1] = (-l1[1] * w[0]) / dd[1];
  for (int j = 2; j < 256; j++) w[j] = (-l1[j] * w[j - 1] - l2[j] * w[j - 2]) / dd[j];
  zz[255] = w[255] / dd[255];
  zz[254] = (w[254] - l1[255] * zz[255]) / dd[254];
  for (int j = 253; j >= 0; j--)
    zz[j] = (w[j] - l1[j + 1] * zz[j + 1] - l2[j + 2] * zz[j + 2]) / dd[j];
  for (int j = 0; j < 256; j++) f.z[j] = zz[j];
  for (int j = 0; j < 256; j++) f.zcf[j] = (float)(zz[j] / zz[0]);
  return f;
}

constexpr FacT FAC_HOST = make_fac();
__constant__ FacT FAC = FAC_HOST;

// ---- build G = C^{-1} - z z^T/z0: 8 blocks x 32 cols, fp64 recurrences in LDS ----
__global__ __launch_bounds__(32) void build_g(float* __restrict__ G, float* __restrict__ zc)
{
  __shared__ double w[256][32];          // 64 KB
  const int t = threadIdx.x;             // col within block
  const int c = blockIdx.x * 32 + t;     // global col
  double w1 = 0.0, w2 = 0.0;
#pragma unroll 4
  for (int j = 0; j < 256; j++) {
    double rhs = (j == c) ? 1.0 : 0.0;
    double wj = (rhs - FAC.l1[j] * w1 - FAC.l2[j] * w2) * FAC.invd[j];
    w[j][t] = wj;
    w2 = w1; w1 = wj;
  }
  const double zr = FAC.z[c] / FAC.z[0];
  double y1 = 0.0, y2 = 0.0;
#pragma unroll 4
  for (int j = 255; j >= 0; j--) {
    double yj = (w[j][t] - FAC.l1[j + 1] * y1 - FAC.l2[j + 2] * y2) * FAC.invd[j];
    G[(size_t)j * 256 + c] = (float)(yj - FAC.z[j] * zr);
    y2 = y1; y1 = yj;
  }
  zc[c] = FAC.zcf[c];
}

// ---------------- transpose + fp32->fp16 convert: in [K][N] -> out [N][K] ----------------
__global__ __launch_bounds__(256) void transpose_cvt(
    const float* __restrict__ in, _Float16* __restrict__ out, int K, int N)
{
  __shared__ float t[32][33];
  const int bk = blockIdx.x * 32, bn = blockIdx.y * 32;
  const int x = threadIdx.x, y = threadIdx.y;
  for (int yy = y; yy < 32; yy += 8) {
    const int k = bk + yy, n = bn + x;
    t[yy][x] = (k < K && n < N) ? in[(size_t)k * N + n] : 0.f;
  }
  __syncthreads();
  for (int yy = y; yy < 32; yy += 8) {
    const int n = bn + yy, k = bk + x;
    if (n < N && k < K) out[(size_t)n * K + k] = (_Float16)t[x][yy];
  }
}

// ---------------- MFMA GEMM: C = A * Bt^T + bias, tile 64x128, 4 waves ----------------
// A: [M][lda] fp32 (A_FP32) or fp16;  Bt: [N][ldk] fp16.  Wave owns 64x32 (4x2 frags).
template<bool A_FP32, bool OUT_H16>
__global__ __launch_bounds__(256) void mfma_gemm(
    const void* __restrict__ Av, const _Float16* __restrict__ Bt,
    const float* __restrict__ bias, void* __restrict__ Cv,
    int M, int Nv, int K, int lda, int ldk, int ldc)
{
  __shared__ _Float16 At[64][36];
  __shared__ _Float16 Bs[128][36];
  const int tid = threadIdx.x;
  const int lane = tid & 63, wid = tid >> 6;
  const int wc = wid;                    // wave -> 32-col slice
  const int lrow = lane & 15, lb = lane >> 4;
  const int m0 = blockIdx.x * 64, n0 = blockIdx.y * 128;
  const int arow = tid >> 2, akq = tid & 3;       // A: 64 rows x 4 k-quads
  const int brow = tid >> 1, bkh = tid & 1;       // B: 128 rows x 2 k-halves

  f32x4 acc[4][2];
#pragma unroll
  for (int i = 0; i < 4; i++)
#pragma unroll
    for (int j = 0; j < 2; j++) acc[i][j] = (f32x4)0.0f;

  const int nsteps = (K + 31) / 32;
  for (int t = 0; t < nsteps; ++t) {
    const int k0 = t * 32;
    // ---- stage A tile [64 rows][32 k] ----
    if (A_FP32) {
      const float* A = (const float*)Av;
#pragma unroll
      for (int i = 0; i < 2; i++) {
        const int k = k0 + akq * 8 + i * 4;
        f16x4 hv = {};
        if (k + 4 <= K) {
          const float4 v = *reinterpret_cast<const float4*>(&A[(size_t)(m0 + arow) * lda + k]);
          hv[0] = (_Float16)v.x; hv[1] = (_Float16)v.y;
          hv[2] = (_Float16)v.z; hv[3] = (_Float16)v.w;
        }
        *reinterpret_cast<f16x4*>(&At[arow][akq * 8 + i * 4]) = hv;
      }
    } else {
      const _Float16* A = (const _Float16*)Av;
#pragma unroll
      for (int i = 0; i < 2; i++) {
        const int k = k0 + akq * 8 + i * 4;
        f16x4 hv = {};
        if (k + 4 <= K) hv = *reinterpret_cast<const f16x4*>(&A[(size_t)(m0 + arow) * lda + k]);
        *reinterpret_cast<f16x4*>(&At[arow][akq * 8 + i * 4]) = hv;
      }
    }
    // ---- stage B tile [128 cols][32 k] from W^T ----
    {
      const int n = n0 + brow;
#pragma unroll
      for (int i = 0; i < 4; i++) {
        const int k = k0 + bkh * 16 + i * 4;
        f16x4 hv = {};
        if (n < Nv && k + 4 <= K)
          hv = *reinterpret_cast<const f16x4*>(&Bt[(size_t)n * ldk + k]);
        *reinterpret_cast<f16x4*>(&Bs[brow][bkh * 16 + i * 4]) = hv;
      }
    }
    __syncthreads();
#pragma unroll
    for (int h = 0; h < 2; h++) {
      f16x4 af[4], bf[2];
#pragma unroll
      for (int i = 0; i < 4; i++)
        af[i] = *reinterpret_cast<const f16x4*>(&At[i * 16 + lrow][h * 16 + lb * 4]);
#pragma unroll
      for (int j = 0; j < 2; j++)
        bf[j] = *reinterpret_cast<const f16x4*>(&Bs[wc * 32 + j * 16 + lrow][h * 16 + lb * 4]);
#pragma unroll
      for (int i = 0; i < 4; i++)
#pragma unroll
        for (int j = 0; j < 2; j++)
          acc[i][j] = __builtin_amdgcn_mfma_f32_16x16x16f16(af[i], bf[j], acc[i][j], 0, 0, 0);
    }
    __syncthreads();
  }
  // ---- epilogue: D col = lane&15, row = 4*(lane>>4)+reg ----
#pragma unroll
  for (int i = 0; i < 4; i++) {
#pragma unroll
    for (int j = 0; j < 2; j++) {
      const int gcol = n0 + wc * 32 + j * 16 + lrow;
      if (gcol < Nv) {
        const float bv = bias[gcol];
#pragma unroll
        for (int r = 0; r < 4; r++) {
          const int grow = m0 + i * 16 + lb * 4 + r;
          float v = acc[i][j][r] + bv;
          if (OUT_H16) {
            v = fmaxf(v, 0.f);
            ((_Float16*)Cv)[(size_t)grow * ldc + gcol] = (_Float16)v;
          } else {
            ((float*)Cv)[(size_t)grow * ldc + gcol] = v;
          }
        }
      }
    }
  }
}

// ---------------- fused QP: init + 5 x (solve GEMM + update) + accum --------------
// One block per 8 rows; thread j = column j. State in LDS/regs; G streamed from L2.
__global__ __launch_bounds__(256) void qp_all(
    const float* __restrict__ NO, const float* __restrict__ ss,
    const float* __restrict__ sinit,
    const float* __restrict__ p_smax, const float* __restrict__ p_smin,
    const float* __restrict__ p_sdmax, const float* __restrict__ p_sdmin,
    const float* __restrict__ p_sddmax, const float* __restrict__ p_sddmin,
    const float* __restrict__ G, const float* __restrict__ zc_,
    float* __restrict__ out, int B)
{
  __shared__ float vs[RPB][256];
  __shared__ float xsA[RPB][260], xsB[RPB][260];
  __shared__ float e1s[RPB][260], e2s[RPB][260], d1s[RPB][260], d2s[RPB][260];
  __shared__ float red[4][RPB][3];
  __shared__ float accPF[2][RPB];

  const int j = threadIdx.x;
  const int r0 = blockIdx.x * RPB;
  const int lane = j & 63, wid = j >> 6;
  const bool h1 = j < 255, h2 = j < 254;
  const float smax = *p_smax, smin = *p_smin;
  const float sdmax = *p_sdmax, sdmin = *p_sdmin;
  const float sddmax = *p_sddmax, sddmin = *p_sddmin;
  const float K0 = smax + smin, K1 = sdmax + sdmin, K2 = sddmax + sddmin;
  const float invT = 20.f, invT2 = 400.f;
  const float zcj = zc_[j];

  const size_t primOff = (size_t)B * NUMV;
  const size_t fpOff = primOff + (size_t)QP_ITERS * B;
  const size_t accPOff = fpOff + (size_t)QP_ITERS * B;
  const size_t accFOff = accPOff + (size_t)B;

  float lam[RPB], ssv[RPB], beqr[RPB], D0i[RPB];
#pragma unroll
  for (int r = 0; r < RPB; r++) {
    lam[r] = NO[(size_t)(r0 + r) * NO_LD + j];
    ssv[r] = ss[(size_t)(r0 + r) * NUMV + j];
    beqr[r] = sinit[r0 + r];
  }
  if (j < RPB) { accPF[0][j] = 0.f; accPF[1][j] = 0.f; }
  if (j < 4) {
#pragma unroll
    for (int r = 0; r < RPB; r++) { xsA[r][256 + j] = 0.f; xsB[r][256 + j] = 0.f; }
  }
  if (j < 2) {
#pragma unroll
    for (int r = 0; r < RPB; r++) {
      e1s[r][j] = 0.f; e2s[r][j] = 0.f; d1s[r][j] = 0.f; d2s[r][j] = 0.f;
    }
  }

  // ---- init: v0 = lam0 + ss + b_aug0 @ A_control ----
#pragma unroll
  for (int r = 0; r < RPB; r++) {
    const float* no = NO + (size_t)(r0 + r) * NO_LD;
    D0i[r] = K0 - fmaxf(0.f, no[256 + j]) + fmaxf(0.f, no[512 + j]);
    float D1 = 0.f, D2 = 0.f;
    if (h1) D1 = K1 - fmaxf(0.f, no[768 + j]) + fmaxf(0.f, no[1023 + j]);
    if (h2) D2 = K2 - fmaxf(0.f, no[1278 + j]) + fmaxf(0.f, no[1532 + j]);
    d1s[r][2 + j] = D1; d2s[r][2 + j] = D2;
  }
  __syncthreads();
#pragma unroll
  for (int r = 0; r < RPB; r++) {
    float qn = D0i[r] + (d1s[r][j + 1] - d1s[r][j + 2]) * invT
                      + (d2s[r][j] - 2.f * d2s[r][j + 1] + d2s[r][j + 2]) * invT2;
    vs[r][j] = lam[r] + ssv[r] + qn;
  }
  __syncthreads();

  float (*xc)[260] = xsA;   // current x
  float (*xp)[260] = xsB;   // previous x

  for (int it = 0; it < QP_ITERS; ++it) {
    // ---- solve: x = G v + beq*zc (G symmetric; G[k][j] coalesced over j) ----
    float acc[RPB];
#pragma unroll
    for (int r = 0; r < RPB; r++) acc[r] = beqr[r] * zcj;
    for (int k0 = 0; k0 < 256; k0 += 4) {
      float4 vr[RPB];
#pragma unroll
      for (int r = 0; r < RPB; r++)
        vr[r] = *reinterpret_cast<const float4*>(&vs[r][k0]);
#pragma unroll
      for (int kk = 0; kk < 4; kk++) {
        const float gv = G[(size_t)(k0 + kk) * 256 + j];
        const float* vp4 = (const float*)&vr[0];
#pragma unroll
        for (int r = 0; r < RPB; r++)
          acc[r] = fmaf(((const float*)&vr[r])[kk], gv, acc[r]);
        (void)vp4;
      }
    }
#pragma unroll
    for (int r = 0; r < RPB; r++) xc[r][j] = acc[r];
    __syncthreads();

    // ---- update, phase 1: stencils ----
    float resP[RPB], fpsP[RPB], rE0[RPB], rD0[RPB];
#pragma unroll
    for (int r = 0; r < RPB; r++) {
      const float x0 = acc[r];
      const float x1 = xc[r][j + 1], x2 = xc[r][j + 2];
      const float v = (x1 - x0) * invT;
      const float aa = (x2 - 2.f * x1 + x0) * invT2;

      float rv0a = fmaxf(0.f, x0 - smax), rv0b = fmaxf(0.f, smin - x0);
      float rv1a = 0.f, rv1b = 0.f, rv2a = 0.f, rv2b = 0.f;
      float E1 = 0.f, E2 = 0.f;
      rE0[r] = rv0a - rv0b;
      if (h1) { rv1a = fmaxf(0.f, v - sdmax); rv1b = fmaxf(0.f, sdmin - v); E1 = rv1a - rv1b; }
      if (h2) { rv2a = fmaxf(0.f, aa - sddmax); rv2b = fmaxf(0.f, sddmin - aa); E2 = rv2a - rv2b; }
      resP[r] = rv0a * rv0a + rv0b * rv0b + rv1a * rv1a + rv1b * rv1b
              + rv2a * rv2a + rv2b * rv2b;

      const float sn0a = fmaxf(0.f, smax - x0), sn0b = fmaxf(0.f, x0 - smin);
      float sn1a = 0.f, sn1b = 0.f, sn2a = 0.f, sn2b = 0.f;
      if (h1) { sn1a = fmaxf(0.f, sdmax - v); sn1b = fmaxf(0.f, v - sdmin); }
      if (h2) { sn2a = fmaxf(0.f, sddmax - aa); sn2b = fmaxf(0.f, aa - sddmin); }

      rD0[r] = fminf(smax, x0) + fmaxf(smin, x0);
      const float D1n = h1 ? (fminf(sdmax, v) + fmaxf(sdmin, v)) : 0.f;
      const float D2n = h2 ? (fminf(sddmax, aa) + fmaxf(sddmin, aa)) : 0.f;

      float sp0a, sp0b, sp1a = 0.f, sp1b = 0.f, sp2a = 0.f, sp2b = 0.f;
      if (it == 0) {
        const float* no = NO + (size_t)(r0 + r) * NO_LD;
        sp0a = fmaxf(0.f, no[256 + j]); sp0b = fmaxf(0.f, no[512 + j]);
        if (h1) { sp1a = fmaxf(0.f, no[768 + j]); sp1b = fmaxf(0.f, no[1023 + j]); }
        if (h2) { sp2a = fmaxf(0.f, no[1278 + j]); sp2b = fmaxf(0.f, no[1532 + j]); }
      } else {
        const float xp0 = xp[r][j], xp1 = xp[r][j + 1], xp2 = xp[r][j + 2];
        const float vp = (xp1 - xp0) * invT;
        const float ap = (xp2 - 2.f * xp1 + xp0) * invT2;
        sp0a = fmaxf(0.f, smax - xp0); sp0b = fmaxf(0.f, xp0 - smin);
        if (h1) { sp1a = fmaxf(0.f, sdmax - vp); sp1b = fmaxf(0.f, vp - sdmin); }
        if (h2) { sp2a = fmaxf(0.f, sddmax - ap); sp2b = fmaxf(0.f, ap - sddmin); }
      }
      const float d0a = sp0a - sn0a, d0b = sp0b - sn0b;
      const float d1a = sp1a - sn1a, d1b = sp1b - sn1b;
      const float d2a = sp2a - sn2a, d2b = sp2b - sn2b;
      fpsP[r] = d0a * d0a + d0b * d0b + d1a * d1a + d1b * d1b + d2a * d2a + d2b * d2b;

      e1s[r][2 + j] = E1; e2s[r][2 + j] = E2;
      d1s[r][2 + j] = D1n; d2s[r][2 + j] = D2n;
    }
    __syncthreads();

    // ---- update, phase 2: lambda, next v, norms ----
    float fplP[RPB];
#pragma unroll
    for (int r = 0; r < RPB; r++) {
      const float lnew = lam[r] - (rE0[r] + (e1s[r][j + 1] - e1s[r][j + 2]) * invT
                                 + (e2s[r][j] - 2.f * e2s[r][j + 1] + e2s[r][j + 2]) * invT2);
      const float dl = lam[r] - lnew;
      fplP[r] = dl * dl;
      lam[r] = lnew;
      const float qn = rD0[r] + (d1s[r][j + 1] - d1s[r][j + 2]) * invT
                     + (d2s[r][j] - 2.f * d2s[r][j + 1] + d2s[r][j + 2]) * invT2;
      vs[r][j] = lnew + ssv[r] + qn;
      if (it == QP_ITERS - 1) out[(size_t)(r0 + r) * NUMV + j] = acc[r];
    }
    // per-row wave reductions
#pragma unroll
    for (int r = 0; r < RPB; r++) {
      float a = resP[r], b = fpsP[r], c = fplP[r];
      for (int o = 32; o > 0; o >>= 1) {
        a += __shfl_down(a, o);
        b += __shfl_down(b, o);
        c += __shfl_down(c, o);
      }
      if (lane == 0) { red[wid][r][0] = a; red[wid][r][1] = b; red[wid][r][2] = c; }
    }
    __syncthreads();
    if (j < RPB) {
      const float r2 = red[0][j][0] + red[1][j][0] + red[2][j][0] + red[3][j][0];
      const float s2 = red[0][j][1] + red[1][j][1] + red[2][j][1] + red[3][j][1];
      const float l2 = red[0][j][2] + red[1][j][2] + red[2][j][2] + red[3][j][2];
      const float pr = sqrtf(r2);
      const float fp = sqrtf(s2) + sqrtf(l2);
      out[primOff + (size_t)it * B + r0 + j] = pr;
      out[fpOff + (size_t)it * B + r0 + j] = fp;
      accPF[0][j] += pr; accPF[1][j] += fp;
    }
    // swap x buffers
    float (*tmp)[260] = xc; xc = xp; xp = tmp;
    __syncthreads();
  }
  if (j < RPB) {
    out[accPOff + r0 + j] = accPF[0][j] * (1.f / QP_ITERS);
    out[accFOff + r0 + j] = accPF[1][j] * (1.f / QP_ITERS);
  }
}

extern "C" void kernel_launch(void* const* d_in, const int* in_sizes, int n_in,
                              void* d_out, int out_size, void* d_ws, size_t ws_size,
                              hipStream_t stream)
{
  const float* inp = (const float*)d_in[0];       // [B][260]
  const float* sinit = (const float*)d_in[1];     // [B][1]
  const float* ssamp = (const float*)d_in[2];     // [B][256]
  const float* p_smax = (const float*)d_in[3];
  const float* p_smin = (const float*)d_in[4];
  const float* p_sdmax = (const float*)d_in[5];
  const float* p_sdmin = (const float*)d_in[6];
  const float* p_sddmax = (const float*)d_in[7];
  const float* p_sddmin = (const float*)d_in[8];
  const float* W1 = (const float*)d_in[11];       // [260][1024]
  const float* b1 = (const float*)d_in[12];       // [1024]
  const float* W2 = (const float*)d_in[13];       // [1024][1786]
  const float* b2 = (const float*)d_in[14];       // [1786]
  float* out = (float*)d_out;

  const int B = in_sizes[1];                      // 4096
  const int IND = in_sizes[9];                    // 260
  const int H = in_sizes[12];                     // 1024
  const int OUTN = in_sizes[14];                  // 1786

  char* ws = (char*)d_ws;
  float* NO = (float*)ws;                                      // [B][1792] fp32
  char* p = ws + (size_t)B * NO_LD * 4;                        // 29,360,128
  _Float16* hH = (_Float16*)p;                                 // [B][1024] fp16
  char* q = p + (size_t)B * H * 2;                             // 37,748,736
  _Float16* W2T = (_Float16*)q;                                // [1786][1024] fp16
  char* q2 = q + (size_t)OUTN * H * 2;                         // 41,406,464
  _Float16* W1T = (_Float16*)q2;                               // [1024][260] fp16
  char* r2 = q2 + (size_t)H * IND * 2 + 1024;                  // ~41,940,480 (aligned region)
  float* G = (float*)r2;                                       // [256][256] fp32
  float* zc = (float*)(r2 + 262144);                           // [256]

  build_g<<<8, 32, 0, stream>>>(G, zc);
  {
    dim3 g((IND + 31) / 32, (H + 31) / 32), blk(32, 8);
    transpose_cvt<<<g, blk, 0, stream>>>(W1, W1T, IND, H);
  }
  {
    dim3 g((H + 31) / 32, (OUTN + 31) / 32), blk(32, 8);
    transpose_cvt<<<g, blk, 0, stream>>>(W2, W2T, H, OUTN);
  }
  {
    dim3 g(B / 64, H / 128);
    mfma_gemm<true, true><<<g, 256, 0, stream>>>(inp, W1T, b1, hH, B, H, IND, IND, IND, H);
  }
  {
    dim3 g(B / 64, (OUTN + 127) / 128);
    mfma_gemm<false, false><<<g, 256, 0, stream>>>(hH, W2T, b2, NO, B, OUTN, H, H, H, NO_LD);
  }
  qp_all<<<B / RPB, 256, 0, stream>>>(NO, ssamp, sinit,
                                      p_smax, p_smin, p_sdmax, p_sdmin,
                                      p_sddmax, p_sddmin, G, zc, out, B);
}

// Round 8
// 292.871 us; speedup vs baseline: 6.3834x; 1.0107x over previous
//
#include <hip/hip_runtime.h>
#include <cstddef>

// learned_qp_solver: B=4096, NUM=256, NC=1530, IND=260, H=1024, OUT=1786, 5 iters.
//
//   KKT solve closed form:  x = G v + (b_eq/z0) z,  G = C^{-1} - z z^T / z0 (symmetric)
//   MLP on matrix cores (fp16 in / fp32 accum, v_mfma_f32_16x16x16_f16).
//   Fused QP kernel: 512 blocks x 512 threads; 8 rows/block; solve split across
//   two 4-wave halves over K (combine via LDS); stencils via shuffles + wave halos.
//
// ws layout (bytes):
//   [0,          29360128)  NO   fp32 [B][1792]
//   [29360128,   37748736)  h    fp16 [B][1024]
//   [37748736,   41406464)  W2T  fp16 [1786][1024]
//   [41406464,   41939456)  W1T  fp16 [1024][260]
//   [41939456,   42201600)  G    fp32 [256][256]
//   [42201600,   42202624)  zc   fp32 [256]

#define NUMV 256
#define QP_ITERS 5
#define NO_LD 1792
#define RPB 8

typedef _Float16 f16x4 __attribute__((ext_vector_type(4)));
typedef float f32x4 __attribute__((ext_vector_type(4)));

// ---------------- compile-time pentadiagonal Cholesky tables ----------------
struct FacT {
  double invd[256];
  double l1[257];
  double l2[258];
  double z[256];
  float  zcf[256];
};

constexpr double csqrt_(double x) {
  double g = (x > 1.0) ? x : 1.0;
  for (int i = 0; i < 64; ++i) g = 0.5 * (g + x / g);
  return g;
}

constexpr FacT make_fac() {
  FacT f{};
  const double T = 0.05, a = 1.0 / (T * T), b2 = a * a;
  double c0[256] = {}, c1[255] = {}, c2[254] = {};
  double dd[256] = {}, l1[256] = {}, l2[256] = {};
  for (int j = 0; j < 256; j++) {
    double cd1 = (j == 0 || j == 255) ? 1.0 : 2.0;
    double cd2 = (j == 0 || j == 255) ? 1.0 : ((j == 1 || j == 254) ? 5.0 : 6.0);
    c0[j] = 3.0 + 2.0 * a * cd1 + 2.0 * b2 * cd2;
  }
  for (int j = 0; j < 255; j++) c1[j] = -2.0 * a + 2.0 * b2 * ((j == 0 || j == 254) ? -2.0 : -4.0);
  for (int j = 0; j < 254; j++) c2[j] = 2.0 * b2;
  dd[0] = csqrt_(c0[0]); l1[0] = 0.0; l2[0] = 0.0;
  l1[1] = c1[0] / dd[0]; l2[1] = 0.0;
  dd[1] = csqrt_(c0[1] - l1[1] * l1[1]);
  for (int j = 2; j < 256; j++) {
    l2[j] = c2[j - 2] / dd[j - 2];
    l1[j] = (c1[j - 1] - l2[j] * l1[j - 1]) / dd[j - 1];
    dd[j] = csqrt_(c0[j] - l1[j] * l1[j] - l2[j] * l2[j]);
  }
  for (int j = 0; j < 256; j++) f.invd[j] = 1.0 / dd[j];
  for (int j = 0; j < 256; j++) f.l1[j] = l1[j];
  f.l1[256] = 0.0;
  for (int j = 0; j < 256; j++) f.l2[j] = l2[j];
  f.l2[256] = 0.0; f.l2[257] = 0.0;
  double w[256] = {}, zz[256] = {};
  w[0] = 1.0 / dd[0];
  w[1] = (-l1[1] * w[0]) / dd[1];
  for (int j = 2; j < 256; j++) w[j] = (-l1[j] * w[j - 1] - l2[j] * w[j - 2]) / dd[j];
  zz[255] = w[255] / dd[255];
  zz[254] = (w[254] - l1[255] * zz[255]) / dd[254];
  for (int j = 253; j >= 0; j--)
    zz[j] = (w[j] - l1[j + 1] * zz[j + 1] - l2[j + 2] * zz[j + 2]) / dd[j];
  for (int j = 0; j < 256; j++) f.z[j] = zz[j];
  for (int j = 0; j < 256; j++) f.zcf[j] = (float)(zz[j] / zz[0]);
  return f;
}

constexpr FacT FAC_HOST = make_fac();
__constant__ FacT FAC = FAC_HOST;

// ---- build G = C^{-1} - z z^T/z0: 8 blocks x 32 cols, fp64 recurrences in LDS ----
__global__ __launch_bounds__(32) void build_g(float* __restrict__ G, float* __restrict__ zc)
{
  __shared__ double w[256][32];
  const int t = threadIdx.x;
  const int c = blockIdx.x * 32 + t;
  double w1 = 0.0, w2 = 0.0;
#pragma unroll 4
  for (int j = 0; j < 256; j++) {
    double rhs = (j == c) ? 1.0 : 0.0;
    double wj = (rhs - FAC.l1[j] * w1 - FAC.l2[j] * w2) * FAC.invd[j];
    w[j][t] = wj;
    w2 = w1; w1 = wj;
  }
  const double zr = FAC.z[c] / FAC.z[0];
  double y1 = 0.0, y2 = 0.0;
#pragma unroll 4
  for (int j = 255; j >= 0; j--) {
    double yj = (w[j][t] - FAC.l1[j + 1] * y1 - FAC.l2[j + 2] * y2) * FAC.invd[j];
    G[(size_t)j * 256 + c] = (float)(yj - FAC.z[j] * zr);
    y2 = y1; y1 = yj;
  }
  zc[c] = FAC.zcf[c];
}

// ---------------- transpose + fp32->fp16 convert: in [K][N] -> out [N][K] ----------------
__global__ __launch_bounds__(256) void transpose_cvt(
    const float* __restrict__ in, _Float16* __restrict__ out, int K, int N)
{
  __shared__ float t[32][33];
  const int bk = blockIdx.x * 32, bn = blockIdx.y * 32;
  const int x = threadIdx.x, y = threadIdx.y;
  for (int yy = y; yy < 32; yy += 8) {
    const int k = bk + yy, n = bn + x;
    t[yy][x] = (k < K && n < N) ? in[(size_t)k * N + n] : 0.f;
  }
  __syncthreads();
  for (int yy = y; yy < 32; yy += 8) {
    const int n = bn + yy, k = bk + x;
    if (n < N && k < K) out[(size_t)n * K + k] = (_Float16)t[x][yy];
  }
}

// ---------------- MFMA GEMM: C = A * Bt^T + bias, tile 64x128, 4 waves ----------------
template<bool A_FP32, bool OUT_H16>
__global__ __launch_bounds__(256) void mfma_gemm(
    const void* __restrict__ Av, const _Float16* __restrict__ Bt,
    const float* __restrict__ bias, void* __restrict__ Cv,
    int M, int Nv, int K, int lda, int ldk, int ldc)
{
  __shared__ _Float16 At[64][36];
  __shared__ _Float16 Bs[128][36];
  const int tid = threadIdx.x;
  const int lane = tid & 63, wid = tid >> 6;
  const int wc = wid;
  const int lrow = lane & 15, lb = lane >> 4;
  const int m0 = blockIdx.x * 64, n0 = blockIdx.y * 128;
  const int arow = tid >> 2, akq = tid & 3;
  const int brow = tid >> 1, bkh = tid & 1;

  f32x4 acc[4][2];
#pragma unroll
  for (int i = 0; i < 4; i++)
#pragma unroll
    for (int j = 0; j < 2; j++) acc[i][j] = (f32x4)0.0f;

  const int nsteps = (K + 31) / 32;
  for (int t = 0; t < nsteps; ++t) {
    const int k0 = t * 32;
    if (A_FP32) {
      const float* A = (const float*)Av;
#pragma unroll
      for (int i = 0; i < 2; i++) {
        const int k = k0 + akq * 8 + i * 4;
        f16x4 hv = {};
        if (k + 4 <= K) {
          const float4 v = *reinterpret_cast<const float4*>(&A[(size_t)(m0 + arow) * lda + k]);
          hv[0] = (_Float16)v.x; hv[1] = (_Float16)v.y;
          hv[2] = (_Float16)v.z; hv[3] = (_Float16)v.w;
        }
        *reinterpret_cast<f16x4*>(&At[arow][akq * 8 + i * 4]) = hv;
      }
    } else {
      const _Float16* A = (const _Float16*)Av;
#pragma unroll
      for (int i = 0; i < 2; i++) {
        const int k = k0 + akq * 8 + i * 4;
        f16x4 hv = {};
        if (k + 4 <= K) hv = *reinterpret_cast<const f16x4*>(&A[(size_t)(m0 + arow) * lda + k]);
        *reinterpret_cast<f16x4*>(&At[arow][akq * 8 + i * 4]) = hv;
      }
    }
    {
      const int n = n0 + brow;
#pragma unroll
      for (int i = 0; i < 4; i++) {
        const int k = k0 + bkh * 16 + i * 4;
        f16x4 hv = {};
        if (n < Nv && k + 4 <= K)
          hv = *reinterpret_cast<const f16x4*>(&Bt[(size_t)n * ldk + k]);
        *reinterpret_cast<f16x4*>(&Bs[brow][bkh * 16 + i * 4]) = hv;
      }
    }
    __syncthreads();
#pragma unroll
    for (int h = 0; h < 2; h++) {
      f16x4 af[4], bf[2];
#pragma unroll
      for (int i = 0; i < 4; i++)
        af[i] = *reinterpret_cast<const f16x4*>(&At[i * 16 + lrow][h * 16 + lb * 4]);
#pragma unroll
      for (int j = 0; j < 2; j++)
        bf[j] = *reinterpret_cast<const f16x4*>(&Bs[wc * 32 + j * 16 + lrow][h * 16 + lb * 4]);
#pragma unroll
      for (int i = 0; i < 4; i++)
#pragma unroll
        for (int j = 0; j < 2; j++)
          acc[i][j] = __builtin_amdgcn_mfma_f32_16x16x16f16(af[i], bf[j], acc[i][j], 0, 0, 0);
    }
    __syncthreads();
  }
#pragma unroll
  for (int i = 0; i < 4; i++) {
#pragma unroll
    for (int j = 0; j < 2; j++) {
      const int gcol = n0 + wc * 32 + j * 16 + lrow;
      if (gcol < Nv) {
        const float bv = bias[gcol];
#pragma unroll
        for (int r = 0; r < 4; r++) {
          const int grow = m0 + i * 16 + lb * 4 + r;
          float v = acc[i][j][r] + bv;
          if (OUT_H16) {
            v = fmaxf(v, 0.f);
            ((_Float16*)Cv)[(size_t)grow * ldc + gcol] = (_Float16)v;
          } else {
            ((float*)Cv)[(size_t)grow * ldc + gcol] = v;
          }
        }
      }
    }
  }
}

// ---------------- fused QP: init + 5 x (solve + update) + accum ----------------
// 512 threads: j = tid&255 (column), half = tid>>8 (K-split for solve).
// Stencils via shuffles + wave-boundary halos; state in registers; v in LDS.
__global__ __launch_bounds__(512, 4) void qp_all(
    const float* __restrict__ NO, const float* __restrict__ ss,
    const float* __restrict__ sinit,
    const float* __restrict__ p_smax, const float* __restrict__ p_smin,
    const float* __restrict__ p_sdmax, const float* __restrict__ p_sdmin,
    const float* __restrict__ p_sddmax, const float* __restrict__ p_sddmin,
    const float* __restrict__ G, const float* __restrict__ zc_,
    float* __restrict__ out, int B)
{
  __shared__ float vs[RPB][256];
  __shared__ float xpart[RPB][256];
  __shared__ float haloXR[4][RPB][2];   // x at lanes 0,1 of each jwave (right halo)
  __shared__ float haloXL[4][RPB][2];   // x at lanes 62,63 (left halo)
  __shared__ float haloPR[4][RPB][2];   // xp at lanes 0,1 (right halo)
  __shared__ float red[4][RPB][3];

  const int tid = threadIdx.x;
  const int j = tid & 255;
  const int half = tid >> 8;
  const int lane = tid & 63;
  const int jw = (tid >> 6) & 3;
  const int r0 = blockIdx.x * RPB;
  const bool h1 = j < 255, h2 = j < 254;
  const float smax = *p_smax, smin = *p_smin;
  const float sdmax = *p_sdmax, sdmin = *p_sdmin;
  const float sddmax = *p_sddmax, sddmin = *p_sddmin;
  const float K0 = smax + smin, K1 = sdmax + sdmin, K2 = sddmax + sddmin;
  const float invT = 20.f, invT2 = 400.f;

  const size_t primOff = (size_t)B * NUMV;
  const size_t fpOff = primOff + (size_t)QP_ITERS * B;
  const size_t accPOff = fpOff + (size_t)QP_ITERS * B;
  const size_t accFOff = accPOff + (size_t)B;

  float lam[RPB], ssv[RPB], beqr[RPB], xp[RPB];
  float zcj = 0.f, accP = 0.f, accF = 0.f;

  if (half == 0) {
    zcj = zc_[j];
#pragma unroll
    for (int r = 0; r < RPB; r++) {
      lam[r] = NO[(size_t)(r0 + r) * NO_LD + j];
      ssv[r] = ss[(size_t)(r0 + r) * NUMV + j];
      beqr[r] = sinit[r0 + r];
      xp[r] = 0.f;
    }
    // ---- init v0 = lam0 + ss + b_aug0 @ A_control (direct shifted loads) ----
#pragma unroll
    for (int r = 0; r < RPB; r++) {
      const float* no = NO + (size_t)(r0 + r) * NO_LD;
      const float D0 = K0 - fmaxf(0.f, no[256 + j]) + fmaxf(0.f, no[512 + j]);
      const float D1j = h1 ? (K1 - fmaxf(0.f, no[768 + j]) + fmaxf(0.f, no[1023 + j])) : 0.f;
      const float D1m = (j >= 1) ? (K1 - fmaxf(0.f, no[768 + j - 1]) + fmaxf(0.f, no[1023 + j - 1])) : 0.f;
      const float D2j = h2 ? (K2 - fmaxf(0.f, no[1278 + j]) + fmaxf(0.f, no[1532 + j])) : 0.f;
      const float D2m1 = (j >= 1 && h1) ? (K2 - fmaxf(0.f, no[1278 + j - 1]) + fmaxf(0.f, no[1532 + j - 1])) : 0.f;
      const float D2m2 = (j >= 2) ? (K2 - fmaxf(0.f, no[1278 + j - 2]) + fmaxf(0.f, no[1532 + j - 2])) : 0.f;
      vs[r][j] = lam[r] + ssv[r] + D0 + (D1m - D1j) * invT + (D2m2 - 2.f * D2m1 + D2j) * invT2;
    }
  }
  __syncthreads();

  for (int it = 0; it < QP_ITERS; ++it) {
    // ---- solve: x = G v + beq*zc, K-split across halves ----
    float acc[RPB];
    if (half == 0) {
#pragma unroll
      for (int r = 0; r < RPB; r++) acc[r] = beqr[r] * zcj;
    } else {
#pragma unroll
      for (int r = 0; r < RPB; r++) acc[r] = 0.f;
    }
    const int kb = half << 7;
#pragma unroll 2
    for (int k0 = 0; k0 < 128; k0 += 4) {
      const float g0 = G[(size_t)(kb + k0 + 0) * 256 + j];
      const float g1 = G[(size_t)(kb + k0 + 1) * 256 + j];
      const float g2 = G[(size_t)(kb + k0 + 2) * 256 + j];
      const float g3 = G[(size_t)(kb + k0 + 3) * 256 + j];
#pragma unroll
      for (int r = 0; r < RPB; r++) {
        const float4 v4 = *reinterpret_cast<const float4*>(&vs[r][kb + k0]);
        acc[r] = fmaf(v4.x, g0, acc[r]);
        acc[r] = fmaf(v4.y, g1, acc[r]);
        acc[r] = fmaf(v4.z, g2, acc[r]);
        acc[r] = fmaf(v4.w, g3, acc[r]);
      }
    }
    if (half == 1) {
#pragma unroll
      for (int r = 0; r < RPB; r++) xpart[r][j] = acc[r];
    }
    __syncthreads();    // S1: xpart ready

    if (half == 0) {
#pragma unroll
      for (int r = 0; r < RPB; r++) {
        acc[r] += xpart[r][j];
        if (lane < 2) {
          haloXR[jw][r][lane] = acc[r];
          haloPR[jw][r][lane] = xp[r];
        }
        if (lane >= 62) haloXL[jw][r][lane - 62] = acc[r];
      }
    }
    __syncthreads();    // S2: halos ready

    if (half == 0) {
#pragma unroll
      for (int r = 0; r < RPB; r++) {
        const float x0 = acc[r];
        // 5-point x window via shuffles + halos
        const float xu1 = __shfl_down(x0, 1), xu2 = __shfl_down(x0, 2);
        const float xd1 = __shfl_up(x0, 1), xd2 = __shfl_up(x0, 2);
        const float nR0 = (jw < 3) ? haloXR[jw + 1][r][0] : 0.f;
        const float nR1 = (jw < 3) ? haloXR[jw + 1][r][1] : 0.f;
        const float nL0 = (jw > 0) ? haloXL[jw - 1][r][0] : 0.f;  // prev lane 62
        const float nL1 = (jw > 0) ? haloXL[jw - 1][r][1] : 0.f;  // prev lane 63
        const float x1 = (lane == 63) ? nR0 : xu1;
        const float x2 = (lane == 62) ? nR0 : ((lane == 63) ? nR1 : xu2);
        const float xm1 = (lane == 0) ? nL1 : xd1;
        const float xm2 = (lane == 0) ? nL0 : ((lane == 1) ? nL1 : xd2);

        const float vj = (x1 - x0) * invT;
        const float aj = (x2 - 2.f * x1 + x0) * invT2;
        const float vm1 = (x0 - xm1) * invT;
        const float am1 = (x1 - 2.f * x0 + xm1) * invT2;
        const float am2 = (x0 - 2.f * xm1 + xm2) * invT2;

        // residual + E at j
        const float rv0a = fmaxf(0.f, x0 - smax), rv0b = fmaxf(0.f, smin - x0);
        const float E0 = rv0a - rv0b;
        float rv1a = 0.f, rv1b = 0.f, rv2a = 0.f, rv2b = 0.f, E1 = 0.f, E2 = 0.f;
        if (h1) { rv1a = fmaxf(0.f, vj - sdmax); rv1b = fmaxf(0.f, sdmin - vj); E1 = rv1a - rv1b; }
        if (h2) { rv2a = fmaxf(0.f, aj - sddmax); rv2b = fmaxf(0.f, sddmin - aj); E2 = rv2a - rv2b; }
        float res2 = rv0a * rv0a + rv0b * rv0b + rv1a * rv1a + rv1b * rv1b
                   + rv2a * rv2a + rv2b * rv2b;

        // E neighbors (recomputed locally)
        const float E1m = (j >= 1) ? (fmaxf(0.f, vm1 - sdmax) - fmaxf(0.f, sdmin - vm1)) : 0.f;
        const float E2m1 = (j >= 1 && h1) ? (fmaxf(0.f, am1 - sddmax) - fmaxf(0.f, sddmin - am1)) : 0.f;
        const float E2m2 = (j >= 2) ? (fmaxf(0.f, am2 - sddmax) - fmaxf(0.f, sddmin - am2)) : 0.f;

        const float dl = E0 + (E1m - E1) * invT + (E2m2 - 2.f * E2m1 + E2) * invT2;
        const float lnew = lam[r] - dl;
        const float fpl2 = dl * dl;

        // s_new at j
        const float sn0a = fmaxf(0.f, smax - x0), sn0b = fmaxf(0.f, x0 - smin);
        float sn1a = 0.f, sn1b = 0.f, sn2a = 0.f, sn2b = 0.f;
        if (h1) { sn1a = fmaxf(0.f, sdmax - vj); sn1b = fmaxf(0.f, vj - sdmin); }
        if (h2) { sn2a = fmaxf(0.f, sddmax - aj); sn2b = fmaxf(0.f, aj - sddmin); }

        // s_prev at j
        float sp0a, sp0b, sp1a = 0.f, sp1b = 0.f, sp2a = 0.f, sp2b = 0.f;
        if (it == 0) {
          const float* no = NO + (size_t)(r0 + r) * NO_LD;
          sp0a = fmaxf(0.f, no[256 + j]); sp0b = fmaxf(0.f, no[512 + j]);
          if (h1) { sp1a = fmaxf(0.f, no[768 + j]); sp1b = fmaxf(0.f, no[1023 + j]); }
          if (h2) { sp2a = fmaxf(0.f, no[1278 + j]); sp2b = fmaxf(0.f, no[1532 + j]); }
        } else {
          const float p0 = xp[r];
          const float pu1 = __shfl_down(p0, 1), pu2 = __shfl_down(p0, 2);
          const float pR0 = (jw < 3) ? haloPR[jw + 1][r][0] : 0.f;
          const float pR1 = (jw < 3) ? haloPR[jw + 1][r][1] : 0.f;
          const float p1 = (lane == 63) ? pR0 : pu1;
          const float p2 = (lane == 62) ? pR0 : ((lane == 63) ? pR1 : pu2);
          const float vp = (p1 - p0) * invT;
          const float ap = (p2 - 2.f * p1 + p0) * invT2;
          sp0a = fmaxf(0.f, smax - p0); sp0b = fmaxf(0.f, p0 - smin);
          if (h1) { sp1a = fmaxf(0.f, sdmax - vp); sp1b = fmaxf(0.f, vp - sdmin); }
          if (h2) { sp2a = fmaxf(0.f, sddmax - ap); sp2b = fmaxf(0.f, ap - sddmin); }
        }
        const float d0a = sp0a - sn0a, d0b = sp0b - sn0b;
        const float d1a = sp1a - sn1a, d1b = sp1b - sn1b;
        const float d2a = sp2a - sn2a, d2b = sp2b - sn2b;
        float fps2 = d0a * d0a + d0b * d0b + d1a * d1a + d1b * d1b
                   + d2a * d2a + d2b * d2b;

        // D terms and next v
        const float D0 = fminf(smax, x0) + fmaxf(smin, x0);
        const float D1 = h1 ? (fminf(sdmax, vj) + fmaxf(sdmin, vj)) : 0.f;
        const float D2 = h2 ? (fminf(sddmax, aj) + fmaxf(sddmin, aj)) : 0.f;
        const float D1m = (j >= 1) ? (fminf(sdmax, vm1) + fmaxf(sdmin, vm1)) : 0.f;
        const float D2m1 = (j >= 1 && h1) ? (fminf(sddmax, am1) + fmaxf(sddmin, am1)) : 0.f;
        const float D2m2 = (j >= 2) ? (fminf(sddmax, am2) + fmaxf(sddmin, am2)) : 0.f;

        vs[r][j] = lnew + ssv[r] + D0 + (D1m - D1) * invT + (D2m2 - 2.f * D2m1 + D2) * invT2;
        lam[r] = lnew;
        xp[r] = x0;
        if (it == QP_ITERS - 1) out[(size_t)(r0 + r) * NUMV + j] = x0;

        // per-row wave reduction, then cross-wave via red
        float a = res2, b = fps2, c = fpl2;
        for (int o = 32; o > 0; o >>= 1) {
          a += __shfl_down(a, o);
          b += __shfl_down(b, o);
          c += __shfl_down(c, o);
        }
        if (lane == 0) { red[jw][r][0] = a; red[jw][r][1] = b; red[jw][r][2] = c; }
      }
    }
    __syncthreads();    // S3: red + vs ready

    if (tid < RPB) {
      const float r2 = red[0][tid][0] + red[1][tid][0] + red[2][tid][0] + red[3][tid][0];
      const float s2 = red[0][tid][1] + red[1][tid][1] + red[2][tid][1] + red[3][tid][1];
      const float l2 = red[0][tid][2] + red[1][tid][2] + red[2][tid][2] + red[3][tid][2];
      const float pr = sqrtf(r2);
      const float fp = sqrtf(s2) + sqrtf(l2);
      out[primOff + (size_t)it * B + r0 + tid] = pr;
      out[fpOff + (size_t)it * B + r0 + tid] = fp;
      accP += pr; accF += fp;
    }
  }
  if (tid < RPB) {
    out[accPOff + r0 + tid] = accP * (1.f / QP_ITERS);
    out[accFOff + r0 + tid] = accF * (1.f / QP_ITERS);
  }
}

extern "C" void kernel_launch(void* const* d_in, const int* in_sizes, int n_in,
                              void* d_out, int out_size, void* d_ws, size_t ws_size,
                              hipStream_t stream)
{
  const float* inp = (const float*)d_in[0];       // [B][260]
  const float* sinit = (const float*)d_in[1];     // [B][1]
  const float* ssamp = (const float*)d_in[2];     // [B][256]
  const float* p_smax = (const float*)d_in[3];
  const float* p_smin = (const float*)d_in[4];
  const float* p_sdmax = (const float*)d_in[5];
  const float* p_sdmin = (const float*)d_in[6];
  const float* p_sddmax = (const float*)d_in[7];
  const float* p_sddmin = (const float*)d_in[8];
  const float* W1 = (const float*)d_in[11];       // [260][1024]
  const float* b1 = (const float*)d_in[12];       // [1024]
  const float* W2 = (const float*)d_in[13];       // [1024][1786]
  const float* b2 = (const float*)d_in[14];       // [1786]
  float* out = (float*)d_out;

  const int B = in_sizes[1];                      // 4096
  const int IND = in_sizes[9];                    // 260
  const int H = in_sizes[12];                     // 1024
  const int OUTN = in_sizes[14];                  // 1786

  char* ws = (char*)d_ws;
  float* NO = (float*)ws;                                      // [B][1792] fp32
  char* p = ws + (size_t)B * NO_LD * 4;                        // 29,360,128
  _Float16* hH = (_Float16*)p;                                 // [B][1024] fp16
  char* q = p + (size_t)B * H * 2;                             // 37,748,736
  _Float16* W2T = (_Float16*)q;                                // [1786][1024] fp16
  char* q2 = q + (size_t)OUTN * H * 2;                         // 41,406,464
  _Float16* W1T = (_Float16*)q2;                               // [1024][260] fp16
  char* r2 = q2 + (size_t)H * IND * 2 + 1024;                  // aligned region
  float* G = (float*)r2;                                       // [256][256] fp32
  float* zc = (float*)(r2 + 262144);                           // [256]

  build_g<<<8, 32, 0, stream>>>(G, zc);
  {
    dim3 g((IND + 31) / 32, (H + 31) / 32), blk(32, 8);
    transpose_cvt<<<g, blk, 0, stream>>>(W1, W1T, IND, H);
  }
  {
    dim3 g((H + 31) / 32, (OUTN + 31) / 32), blk(32, 8);
    transpose_cvt<<<g, blk, 0, stream>>>(W2, W2T, H, OUTN);
  }
  {
    dim3 g(B / 64, H / 128);
    mfma_gemm<true, true><<<g, 256, 0, stream>>>(inp, W1T, b1, hH, B, H, IND, IND, IND, H);
  }
  {
    dim3 g(B / 64, (OUTN + 127) / 128);
    mfma_gemm<false, false><<<g, 256, 0, stream>>>(hH, W2T, b2, NO, B, OUTN, H, H, H, NO_LD);
  }
  qp_all<<<B / RPB, 512, 0, stream>>>(NO, ssamp, sinit,
                                      p_smax, p_smin, p_sdmax, p_sdmin,
                                      p_sddmax, p_sddmin, G, zc, out, B);
}